// Round 1
// baseline (2087.119 us; speedup 1.0000x reference)
//
#include <hip/hip_runtime.h>
#include <hip/hip_bf16.h>

#define N_PTS 2048
#define BATCH 2
#define KNN 40

__device__ __forceinline__ float lrelu(float v, float s) {
    return v >= 0.f ? v : s * v;
}

// ---------------- prefix: conv (5,3)/(5,1) + lrelu(0.01) -> H (B,N,2) ----------------
__global__ void prefix_kernel(const float* __restrict__ x, const float* __restrict__ Wc,
                              const float* __restrict__ bc, float* __restrict__ H) {
    int t = blockIdx.x * 256 + threadIdx.x;
    if (t >= BATCH * N_PTS) return;
    int b = t >> 11, n = t & 2047;
    #pragma unroll
    for (int oh = 0; oh < 2; ++oh) {
        float acc = bc[0];
        #pragma unroll
        for (int kh = 0; kh < 5; ++kh) {
            const float* xr = x + ((size_t)b * 10 + oh * 5 + kh) * N_PTS;
            #pragma unroll
            for (int kw = 0; kw < 3; ++kw) {
                int nn = n + kw - 1;
                if (nn >= 0 && nn < N_PTS) acc += xr[nn] * Wc[kh * 3 + kw];
            }
        }
        H[(size_t)t * 2 + oh] = lrelu(acc, 0.01f);
    }
}

// ---------------- xx[b,n] = sum_c X[b,n,c]^2 ----------------
__global__ void xx_kernel(const float* __restrict__ X, int S, long bsX, int C,
                          float* __restrict__ XX) {
    int t = blockIdx.x * 256 + threadIdx.x;
    if (t >= BATCH * N_PTS) return;
    int b = t >> 11, n = t & 2047;
    const float* row = X + (size_t)b * bsX + (size_t)n * S;
    float s = 0.f;
    for (int c = 0; c < C; ++c) { float v = row[c]; s += v * v; }
    XX[t] = s;
}

// ---------------- gram: negd[n,m] = 2*dot(X[n],X[m]) - xx[n] - xx[m] (one batch) ----------------
__global__ __launch_bounds__(256) void gram_kernel(const float* __restrict__ X, int S, int C,
                                                   const float* __restrict__ xx,
                                                   float* __restrict__ negd) {
    __shared__ float As[64][36];
    __shared__ float Bs[64][36];
    int tid = threadIdx.x;
    int r0 = blockIdx.y * 64, c0 = blockIdx.x * 64;
    int ty = tid >> 4, tx = tid & 15;
    float acc[4][4] = {};
    for (int k0 = 0; k0 < C; k0 += 32) {
        int kc = C - k0; if (kc > 32) kc = 32;
        __syncthreads();
        for (int i = tid; i < 64 * 32; i += 256) {
            int r = i >> 5, k = i & 31;
            float va = 0.f, vb = 0.f;
            if (k < kc) {
                va = X[(size_t)(r0 + r) * S + k0 + k];
                vb = X[(size_t)(c0 + r) * S + k0 + k];
            }
            As[r][k] = va; Bs[r][k] = vb;
        }
        __syncthreads();
        #pragma unroll
        for (int k = 0; k < 32; k += 4) {
            float4 a[4], b[4];
            #pragma unroll
            for (int i = 0; i < 4; ++i) a[i] = *(const float4*)&As[ty * 4 + i][k];
            #pragma unroll
            for (int j = 0; j < 4; ++j) b[j] = *(const float4*)&Bs[tx * 4 + j][k];
            #pragma unroll
            for (int i = 0; i < 4; ++i)
                #pragma unroll
                for (int j = 0; j < 4; ++j)
                    acc[i][j] += a[i].x * b[j].x + a[i].y * b[j].y + a[i].z * b[j].z + a[i].w * b[j].w;
        }
    }
    #pragma unroll
    for (int i = 0; i < 4; ++i) {
        int r = r0 + ty * 4 + i;
        float xr = xx[r];
        #pragma unroll
        for (int j = 0; j < 4; ++j) {
            int c = c0 + tx * 4 + j;
            negd[(size_t)r * N_PTS + c] = 2.0f * acc[i][j] - xr - xx[c];
        }
    }
}

// ---------------- top-40 per row (one wave per row) ----------------
__global__ __launch_bounds__(64) void topk_kernel(const float* __restrict__ negd,
                                                  int* __restrict__ idx_out) {
    __shared__ float v[N_PTS];
    int n = blockIdx.x;
    int lane = threadIdx.x;
    const float* row = negd + (size_t)n * N_PTS;
    for (int j = lane; j < N_PTS; j += 64) v[j] = row[j];
    __syncthreads();
    for (int k = 0; k < KNN; ++k) {
        float best = -3.4e38f; int bidx = N_PTS;
        for (int j = lane; j < N_PTS; j += 64) {
            float val = v[j];
            if (val > best || (val == best && j < bidx)) { best = val; bidx = j; }
        }
        #pragma unroll
        for (int off = 32; off; off >>= 1) {
            float ov = __shfl_xor(best, off);
            int oi = __shfl_xor(bidx, off);
            if (ov > best || (ov == best && oi < bidx)) { best = ov; bidx = oi; }
        }
        if (lane == 0) { idx_out[n * KNN + k] = bidx; v[bidx] = -3.4e38f; }
        __syncthreads();
    }
}

// ---------------- YaT = X @ Wa^T ; ZT = X @ Wb^T - YaT + bias  (layout (B,N,O)) ----------------
__global__ __launch_bounds__(256) void ya_z_kernel(const float* __restrict__ X, int S, long bsX,
                                                   int C, int O, const float* __restrict__ W,
                                                   const float* __restrict__ bias,
                                                   float* __restrict__ YaT, float* __restrict__ ZT) {
    __shared__ float Xs[64][36];
    __shared__ float Was[64][36];
    __shared__ float Wbs[64][36];
    int b = blockIdx.z;
    const float* Xb = X + (size_t)b * bsX;
    int n0 = blockIdx.x * 64, o0 = blockIdx.y * 64;
    int tid = threadIdx.x, ty = tid >> 4, tx = tid & 15;
    float aa[4][4] = {}, ab[4][4] = {};
    for (int k0 = 0; k0 < C; k0 += 32) {
        int kc = C - k0; if (kc > 32) kc = 32;
        __syncthreads();
        for (int i = tid; i < 64 * 32; i += 256) {
            int r = i >> 5, k = i & 31;
            float vx = 0.f, va = 0.f, vb = 0.f;
            if (k < kc) {
                vx = Xb[(size_t)(n0 + r) * S + k0 + k];
                int o = o0 + r;
                if (o < O) {
                    va = W[(size_t)o * 2 * C + k0 + k];
                    vb = W[(size_t)o * 2 * C + C + k0 + k];
                }
            }
            Xs[r][k] = vx; Was[r][k] = va; Wbs[r][k] = vb;
        }
        __syncthreads();
        #pragma unroll
        for (int k = 0; k < 32; k += 4) {
            float4 xv[4], wa[4], wb[4];
            #pragma unroll
            for (int i = 0; i < 4; ++i) xv[i] = *(const float4*)&Xs[ty * 4 + i][k];
            #pragma unroll
            for (int j = 0; j < 4; ++j) {
                wa[j] = *(const float4*)&Was[tx * 4 + j][k];
                wb[j] = *(const float4*)&Wbs[tx * 4 + j][k];
            }
            #pragma unroll
            for (int i = 0; i < 4; ++i)
                #pragma unroll
                for (int j = 0; j < 4; ++j) {
                    aa[i][j] += xv[i].x * wa[j].x + xv[i].y * wa[j].y + xv[i].z * wa[j].z + xv[i].w * wa[j].w;
                    ab[i][j] += xv[i].x * wb[j].x + xv[i].y * wb[j].y + xv[i].z * wb[j].z + xv[i].w * wb[j].w;
                }
        }
    }
    #pragma unroll
    for (int i = 0; i < 4; ++i) {
        int n = n0 + ty * 4 + i;
        #pragma unroll
        for (int j = 0; j < 4; ++j) {
            int o = o0 + tx * 4 + j;
            if (o < O) {
                size_t off = ((size_t)b * N_PTS + n) * O + o;
                YaT[off] = aa[i][j];
                ZT[off] = ab[i][j] - aa[i][j] + bias[o];
            }
        }
    }
}

// ---------------- out[n,o] = max_k lrelu(YaT[idx[n,k],o] + ZT[n,o], 0.2) ----------------
__global__ __launch_bounds__(256) void edge_reduce_kernel(const float* __restrict__ YaT,
                                                          const float* __restrict__ ZT,
                                                          const int* __restrict__ IDX, int O,
                                                          float* __restrict__ CATp, int coloff) {
    int b = blockIdx.y;
    int tid = threadIdx.x;
    int n = blockIdx.x * (256 / O) + tid / O;
    int o = tid & (O - 1);
    const float* Ya_b = YaT + (size_t)b * N_PTS * O;
    float z = ZT[((size_t)b * N_PTS + n) * O + o];
    const int* ir = IDX + ((size_t)b * N_PTS + n) * KNN;
    float acc = -3.4e38f;
    #pragma unroll 8
    for (int k = 0; k < KNN; ++k) {
        int m = ir[k];
        float v = Ya_b[(size_t)m * O + o] + z;
        acc = fmaxf(acc, lrelu(v, 0.2f));
    }
    CATp[((size_t)b * N_PTS + n) * 512 + coloff + o] = acc;
}

// ---------------- g partials: lrelu(W5 @ cat + b5) with max over 64-row tile ----------------
__global__ __launch_bounds__(256) void w5max_kernel(const float* __restrict__ CATp,
                                                    const float* __restrict__ W5,
                                                    const float* __restrict__ b5,
                                                    float* __restrict__ PART) {
    __shared__ float Cs[64][36];
    __shared__ float Ws[64][36];
    __shared__ float red[16][64];
    int b = blockIdx.z;
    int n0 = blockIdx.x * 64, o0 = blockIdx.y * 64;
    int tid = threadIdx.x, ty = tid >> 4, tx = tid & 15;
    const float* Cb = CATp + (size_t)b * N_PTS * 512;
    float acc[4][4] = {};
    for (int k0 = 0; k0 < 512; k0 += 32) {
        __syncthreads();
        for (int i = tid; i < 64 * 32; i += 256) {
            int r = i >> 5, k = i & 31;
            Cs[r][k] = Cb[(size_t)(n0 + r) * 512 + k0 + k];
            Ws[r][k] = W5[(size_t)(o0 + r) * 512 + k0 + k];
        }
        __syncthreads();
        #pragma unroll
        for (int k = 0; k < 32; k += 4) {
            float4 a[4], w[4];
            #pragma unroll
            for (int i = 0; i < 4; ++i) a[i] = *(const float4*)&Cs[ty * 4 + i][k];
            #pragma unroll
            for (int j = 0; j < 4; ++j) w[j] = *(const float4*)&Ws[tx * 4 + j][k];
            #pragma unroll
            for (int i = 0; i < 4; ++i)
                #pragma unroll
                for (int j = 0; j < 4; ++j)
                    acc[i][j] += a[i].x * w[j].x + a[i].y * w[j].y + a[i].z * w[j].z + a[i].w * w[j].w;
        }
    }
    #pragma unroll
    for (int j = 0; j < 4; ++j) {
        int o = o0 + tx * 4 + j;
        float bo = b5[o];
        float m = -3.4e38f;
        #pragma unroll
        for (int i = 0; i < 4; ++i) m = fmaxf(m, lrelu(acc[i][j] + bo, 0.2f));
        red[ty][tx * 4 + j] = m;
    }
    __syncthreads();
    if (tid < 64) {
        float m = red[0][tid];
        #pragma unroll
        for (int t = 1; t < 16; ++t) m = fmaxf(m, red[t][tid]);
        PART[((size_t)b * 32 + blockIdx.x) * 1024 + o0 + tid] = m;
    }
}

__global__ void greduce_kernel(const float* __restrict__ PART, float* __restrict__ G) {
    int t = blockIdx.x * 256 + threadIdx.x;
    if (t >= BATCH * 1024) return;
    int b = t >> 10, o = t & 1023;
    const float* p = PART + (size_t)b * 32 * 1024 + o;
    float m = -3.4e38f;
    for (int nb = 0; nb < 32; ++nb) m = fmaxf(m, p[(size_t)nb * 1024]);
    G[t] = m;
}

// ---------------- FC: D0[b,j] = lrelu(g[b,:] . Wfc[j,:] + bfc[j]) ----------------
__global__ __launch_bounds__(256) void fc_kernel(const float* __restrict__ G,
                                                 const float* __restrict__ Wfc,
                                                 const float* __restrict__ bfc,
                                                 float* __restrict__ D0) {
    __shared__ float gl[2][1024];
    int tid = threadIdx.x;
    for (int i = tid; i < 2048; i += 256) gl[i >> 10][i & 1023] = G[i];
    __syncthreads();
    int wave = tid >> 6, lane = tid & 63;
    int j = blockIdx.x * 4 + wave;
    const float* wr = Wfc + (size_t)j * 1024;
    float a0 = 0.f, a1 = 0.f;
    for (int i = lane; i < 1024; i += 64) {
        float w = wr[i];
        a0 += w * gl[0][i];
        a1 += w * gl[1][i];
    }
    #pragma unroll
    for (int off = 32; off; off >>= 1) { a0 += __shfl_xor(a0, off); a1 += __shfl_xor(a1, off); }
    if (lane == 0) {
        float bb = bfc[j];
        D0[j] = lrelu(a0 + bb, 0.2f);
        D0[16384 + j] = lrelu(a1 + bb, 0.2f);
    }
}

// ---------------- fused up2 + conv3x3 (+ optional lrelu 0.2) ----------------
__global__ void upconv_kernel(const float* __restrict__ in, const float* __restrict__ W,
                              const float* __restrict__ bias, float* __restrict__ out,
                              int Ci, int Co, int Hi, int Wi, int total, int doRelu) {
    int t = blockIdx.x * 256 + threadIdx.x;
    if (t >= total) return;
    int Ho = Hi * 2, Wo = Wi * 2;
    int xo = t % Wo;
    int yo = (t / Wo) % Ho;
    int co = (t / (Wo * Ho)) % Co;
    int b = t / (Wo * Ho * Co);
    float acc = bias[co];
    const float* inb = in + (size_t)b * Ci * Hi * Wi;
    const float* wco = W + (size_t)co * Ci * 9;
    for (int ci = 0; ci < Ci; ++ci) {
        const float* ip = inb + (size_t)ci * Hi * Wi;
        const float* wp = wco + ci * 9;
        #pragma unroll
        for (int dy = 0; dy < 3; ++dy) {
            int yy = yo + dy - 1;
            if (yy < 0 || yy >= Ho) continue;
            const float* row = ip + (size_t)(yy >> 1) * Wi;
            #pragma unroll
            for (int dx = 0; dx < 3; ++dx) {
                int xx = xo + dx - 1;
                if (xx < 0 || xx >= Wo) continue;
                acc += row[xx >> 1] * wp[dy * 3 + dx];
            }
        }
    }
    if (doRelu) acc = lrelu(acc, 0.2f);
    out[t] = acc;
}

extern "C" void kernel_launch(void* const* d_in, const int* in_sizes, int n_in,
                              void* d_out, int out_size, void* d_ws, size_t ws_size,
                              hipStream_t stream) {
    const float* x   = (const float*)d_in[0];
    const float* Wc  = (const float*)d_in[1];
    const float* bc  = (const float*)d_in[2];
    const float* W1  = (const float*)d_in[3];
    const float* b1  = (const float*)d_in[4];
    const float* W2  = (const float*)d_in[5];
    const float* b2  = (const float*)d_in[6];
    const float* W3  = (const float*)d_in[7];
    const float* b3  = (const float*)d_in[8];
    const float* W4  = (const float*)d_in[9];
    const float* b4  = (const float*)d_in[10];
    const float* W5  = (const float*)d_in[11];
    const float* b5  = (const float*)d_in[12];
    const float* Wfc = (const float*)d_in[13];
    const float* bfc = (const float*)d_in[14];
    const float* Wd1 = (const float*)d_in[15];
    const float* bd1 = (const float*)d_in[16];
    const float* Wd2 = (const float*)d_in[17];
    const float* bd2 = (const float*)d_in[18];
    const float* Wd3 = (const float*)d_in[19];
    const float* bd3 = (const float*)d_in[20];
    float* out = (float*)d_out;

    char* ws = (char*)d_ws;
    float* Hb   = (float*)(ws + 0);          // (B,N,2)      32 KB
    float* CAT  = (float*)(ws + 32768);      // (B,N,512)    8 MB
    float* YaT  = (float*)(ws + 8421376);    // (B,N,256)    4 MB
    float* ZT   = (float*)(ws + 12615680);   // (B,N,256)    4 MB
    float* NEGD = (float*)(ws + 16809984);   // (N,N)        16 MB (reused per batch)
    float* XX   = (float*)(ws + 33587200);   // (B,N)
    int*   IDX  = (int*)  (ws + 33603584);   // (B,N,40)
    float* PART = (float*)(ws + 34258944);   // (B,32,1024)
    float* G    = (float*)(ws + 34521088);   // (B,1024)
    float* D0   = (float*)(ws + 34529280);   // (B,16384)
    float* DEC1 = (float*)(ws + 34660352);   // (B,32,32,32)
    float* DEC2 = (float*)(ws + 34922496);   // (B,16,64,64)

    prefix_kernel<<<16, 256, 0, stream>>>(x, Wc, bc, Hb);

    // one EdgeConv stage
    auto stage = [&](const float* X, int S, long bsX, int C, int O,
                     const float* W, const float* bias, int coloff) {
        xx_kernel<<<16, 256, 0, stream>>>(X, S, bsX, C, XX);
        for (int b = 0; b < BATCH; ++b) {
            gram_kernel<<<dim3(32, 32), 256, 0, stream>>>(X + (size_t)b * bsX, S, C,
                                                          XX + b * N_PTS, NEGD);
            topk_kernel<<<N_PTS, 64, 0, stream>>>(NEGD, IDX + (size_t)b * N_PTS * KNN);
        }
        ya_z_kernel<<<dim3(32, (O + 63) / 64, BATCH), 256, 0, stream>>>(X, S, bsX, C, O, W, bias,
                                                                        YaT, ZT);
        edge_reduce_kernel<<<dim3(N_PTS * O / 256, BATCH), 256, 0, stream>>>(YaT, ZT, IDX, O,
                                                                             CAT, coloff);
    };

    stage(Hb,        2,   (long)N_PTS * 2,   2,   64,  W1, b1, 0);
    stage(CAT + 0,   512, (long)N_PTS * 512, 64,  64,  W2, b2, 64);
    stage(CAT + 64,  512, (long)N_PTS * 512, 64,  128, W3, b3, 128);
    stage(CAT + 128, 512, (long)N_PTS * 512, 128, 256, W4, b4, 256);

    w5max_kernel<<<dim3(32, 16, BATCH), 256, 0, stream>>>(CAT, W5, b5, PART);
    greduce_kernel<<<8, 256, 0, stream>>>(PART, G);
    fc_kernel<<<4096, 256, 0, stream>>>(G, Wfc, bfc, D0);

    upconv_kernel<<<(2 * 32 * 32 * 32 + 255) / 256, 256, 0, stream>>>(D0, Wd1, bd1, DEC1,
                                                                      64, 32, 16, 16,
                                                                      2 * 32 * 32 * 32, 1);
    upconv_kernel<<<(2 * 16 * 64 * 64 + 255) / 256, 256, 0, stream>>>(DEC1, Wd2, bd2, DEC2,
                                                                      32, 16, 32, 32,
                                                                      2 * 16 * 64 * 64, 1);
    upconv_kernel<<<(2 * 1 * 128 * 128 + 255) / 256, 256, 0, stream>>>(DEC2, Wd3, bd3, out,
                                                                       16, 1, 64, 64,
                                                                       2 * 1 * 128 * 128, 0);
}

// Round 2
// 754.689 us; speedup vs baseline: 2.7655x; 2.7655x over previous
//
#include <hip/hip_runtime.h>
#include <hip/hip_bf16.h>

#define N_PTS 2048
#define BATCH 2
#define KNN 40

__device__ __forceinline__ float lrelu(float v, float s) {
    return v >= 0.f ? v : s * v;
}

// ---------------- prefix: conv (5,3)/(5,1) + lrelu(0.01) -> H (B,N,2) ----------------
__global__ void prefix_kernel(const float* __restrict__ x, const float* __restrict__ Wc,
                              const float* __restrict__ bc, float* __restrict__ H) {
    int t = blockIdx.x * 256 + threadIdx.x;
    if (t >= BATCH * N_PTS) return;
    int b = t >> 11, n = t & 2047;
    #pragma unroll
    for (int oh = 0; oh < 2; ++oh) {
        float acc = bc[0];
        #pragma unroll
        for (int kh = 0; kh < 5; ++kh) {
            const float* xr = x + ((size_t)b * 10 + oh * 5 + kh) * N_PTS;
            #pragma unroll
            for (int kw = 0; kw < 3; ++kw) {
                int nn = n + kw - 1;
                if (nn >= 0 && nn < N_PTS) acc += xr[nn] * Wc[kh * 3 + kw];
            }
        }
        H[(size_t)t * 2 + oh] = lrelu(acc, 0.01f);
    }
}

// ---------------- xx[b,n] = sum_c X[b,n,c]^2 ----------------
__global__ void xx_kernel(const float* __restrict__ X, int S, long bsX, int C,
                          float* __restrict__ XX) {
    int t = blockIdx.x * 256 + threadIdx.x;
    if (t >= BATCH * N_PTS) return;
    int b = t >> 11, n = t & 2047;
    const float* row = X + (size_t)b * bsX + (size_t)n * S;
    float s = 0.f;
    for (int c = 0; c < C; ++c) { float v = row[c]; s += v * v; }
    XX[t] = s;
}

// ---------------- gram: negd[n,m] = 2*dot(X[n],X[m]) - xx[n] - xx[m] (one batch) ----------
// transposed-LDS outer-product microkernel, conflict-free main-loop reads
template<int C, int STAGE>
__global__ __launch_bounds__(256) void gram_kernel(const float* __restrict__ X, int S,
                                                   const float* __restrict__ xx,
                                                   float* __restrict__ negd) {
    constexpr int KC = (C < 32) ? C : 32;
    __shared__ float AsT[KC][68];
    __shared__ float BsT[KC][68];
    int tid = threadIdx.x;
    int r0 = blockIdx.y * 64, c0 = blockIdx.x * 64;
    int ty = tid >> 4, tx = tid & 15;
    float acc[4][4] = {};
    for (int k0 = 0; k0 < C; k0 += KC) {
        __syncthreads();
        for (int i = tid; i < 64 * KC; i += 256) {
            int r = i / KC, c = i % KC;
            AsT[c][r] = X[(size_t)(r0 + r) * S + k0 + c];
            BsT[c][r] = X[(size_t)(c0 + r) * S + k0 + c];
        }
        __syncthreads();
        #pragma unroll
        for (int k = 0; k < KC; ++k) {
            float4 a = *(const float4*)&AsT[k][ty * 4];
            float4 b = *(const float4*)&BsT[k][tx * 4];
            #pragma unroll
            for (int i = 0; i < 4; ++i)
                #pragma unroll
                for (int j = 0; j < 4; ++j)
                    acc[i][j] += (&a.x)[i] * (&b.x)[j];
        }
    }
    #pragma unroll
    for (int i = 0; i < 4; ++i) {
        int r = r0 + ty * 4 + i;
        float xr = xx[r];
        #pragma unroll
        for (int j = 0; j < 4; ++j) {
            int c = c0 + tx * 4 + j;
            negd[(size_t)r * N_PTS + c] = 2.0f * acc[i][j] - xr - xx[c];
        }
    }
}

// ---------------- top-40 per row: 3-round radix select (exact, index-ascending ties) ----
template<int STAGE>
__global__ __launch_bounds__(256) void topk_kernel(const float* __restrict__ negd,
                                                   int* __restrict__ idx_out) {
    __shared__ unsigned keys[N_PTS];
    __shared__ unsigned hist[4096];
    __shared__ unsigned csum[256];
    __shared__ unsigned sc[4];
    int n = blockIdx.x;
    int tid = threadIdx.x;
    const float* row = negd + (size_t)n * N_PTS;
    for (int j = tid; j < N_PTS; j += 256) {
        unsigned u = __float_as_uint(row[j]);
        keys[j] = (u & 0x80000000u) ? ~u : (u | 0x80000000u);
    }
    unsigned r = KNN;
    // ---- round 1: bits [31:20], 4096 bins ----
    for (int i = tid; i < 4096; i += 256) hist[i] = 0u;
    __syncthreads();
    for (int j = tid; j < N_PTS; j += 256) atomicAdd(&hist[keys[j] >> 20], 1u);
    __syncthreads();
    { unsigned s = 0; for (int q = 0; q < 16; ++q) s += hist[tid * 16 + q]; csum[tid] = s; }
    __syncthreads();
    for (int st = 1; st < 256; st <<= 1) {
        unsigned v = (tid + st < 256) ? csum[tid + st] : 0u;
        __syncthreads();
        csum[tid] += v;
        __syncthreads();
    }
    {
        unsigned St = csum[tid], Sn = (tid < 255) ? csum[tid + 1] : 0u;
        if (St >= r && Sn < r) { sc[0] = (unsigned)tid; sc[1] = r - Sn; }
    }
    __syncthreads();
    if (tid == 0) {
        int c = (int)sc[0]; unsigned rc = sc[1];
        unsigned cum = 0; int b = c * 16 + 15;
        for (;; --b) { cum += hist[b]; if (cum >= rc) break; }
        sc[0] = (unsigned)b;
        sc[1] = rc - (cum - hist[b]);
    }
    __syncthreads();
    unsigned p1 = sc[0]; r = sc[1];
    // ---- round 2: bits [19:8] among prefix==p1, 4096 bins ----
    __syncthreads();
    for (int i = tid; i < 4096; i += 256) hist[i] = 0u;
    __syncthreads();
    for (int j = tid; j < N_PTS; j += 256)
        if ((keys[j] >> 20) == p1) atomicAdd(&hist[(keys[j] >> 8) & 0xFFFu], 1u);
    __syncthreads();
    { unsigned s = 0; for (int q = 0; q < 16; ++q) s += hist[tid * 16 + q]; csum[tid] = s; }
    __syncthreads();
    for (int st = 1; st < 256; st <<= 1) {
        unsigned v = (tid + st < 256) ? csum[tid + st] : 0u;
        __syncthreads();
        csum[tid] += v;
        __syncthreads();
    }
    {
        unsigned St = csum[tid], Sn = (tid < 255) ? csum[tid + 1] : 0u;
        if (St >= r && Sn < r) { sc[0] = (unsigned)tid; sc[1] = r - Sn; }
    }
    __syncthreads();
    if (tid == 0) {
        int c = (int)sc[0]; unsigned rc = sc[1];
        unsigned cum = 0; int b = c * 16 + 15;
        for (;; --b) { cum += hist[b]; if (cum >= rc) break; }
        sc[0] = (unsigned)b;
        sc[1] = rc - (cum - hist[b]);
    }
    __syncthreads();
    unsigned p2 = (p1 << 12) | sc[0]; r = sc[1];
    // ---- round 3: bits [7:0] among prefix==p2, 256 bins ----
    __syncthreads();
    for (int i = tid; i < 256; i += 256) hist[i] = 0u;
    __syncthreads();
    for (int j = tid; j < N_PTS; j += 256)
        if ((keys[j] >> 8) == p2) atomicAdd(&hist[keys[j] & 0xFFu], 1u);
    __syncthreads();
    csum[tid] = hist[tid];
    __syncthreads();
    for (int st = 1; st < 256; st <<= 1) {
        unsigned v = (tid + st < 256) ? csum[tid + st] : 0u;
        __syncthreads();
        csum[tid] += v;
        __syncthreads();
    }
    {
        unsigned St = csum[tid], Sn = (tid < 255) ? csum[tid + 1] : 0u;
        if (St >= r && Sn < r) { sc[0] = (unsigned)tid; sc[1] = r - Sn; }
    }
    __syncthreads();
    unsigned T = (p2 << 8) | sc[0];
    unsigned r3 = sc[1];               // number to take from keys == T (>=1)
    // ---- collect ----
    if (tid == 0) sc[2] = 0u;
    __syncthreads();
    int* out = idx_out + (size_t)n * KNN;
    for (int j = tid; j < N_PTS; j += 256)
        if (keys[j] > T) out[atomicAdd(&sc[2], 1u)] = j;
    __syncthreads();
    int last = -1;
    for (unsigned t = 0; t < r3; ++t) {
        unsigned m = 0xFFFFFFFFu;
        for (int j = tid; j < N_PTS; j += 256)
            if (keys[j] == T && j > last) { m = (unsigned)j; break; }
        csum[tid] = m;
        __syncthreads();
        for (int st = 128; st >= 1; st >>= 1) {
            if (tid < st) csum[tid] = min(csum[tid], csum[tid + st]);
            __syncthreads();
        }
        if (tid == 0) {
            out[KNN - (int)r3 + (int)t] = (int)csum[0];
            sc[3] = csum[0];
        }
        __syncthreads();
        last = (int)sc[3];
    }
}

// ---------------- YaT = X @ Wa^T ; ZT = X @ Wb^T - YaT + bias  (layout (B,N,O)) ---------
template<int C, int O, int STAGE>
__global__ __launch_bounds__(256) void ya_z_kernel(const float* __restrict__ X, int S, long bsX,
                                                   const float* __restrict__ W,
                                                   const float* __restrict__ bias,
                                                   float* __restrict__ YaT, float* __restrict__ ZT) {
    constexpr int KC = (C < 32) ? C : 32;
    __shared__ float XsT[KC][68];
    __shared__ float WaT[KC][68];
    __shared__ float WbT[KC][68];
    int b = blockIdx.z;
    const float* Xb = X + (size_t)b * bsX;
    int n0 = blockIdx.x * 64, o0 = blockIdx.y * 64;
    int tid = threadIdx.x, ty = tid >> 4, tx = tid & 15;
    float aa[4][4] = {}, ab[4][4] = {};
    for (int k0 = 0; k0 < C; k0 += KC) {
        __syncthreads();
        for (int i = tid; i < 64 * KC; i += 256) {
            int r = i / KC, c = i % KC;
            XsT[c][r] = Xb[(size_t)(n0 + r) * S + k0 + c];
            WaT[c][r] = W[(size_t)(o0 + r) * 2 * C + k0 + c];
            WbT[c][r] = W[(size_t)(o0 + r) * 2 * C + C + k0 + c];
        }
        __syncthreads();
        #pragma unroll
        for (int k = 0; k < KC; ++k) {
            float4 xv = *(const float4*)&XsT[k][ty * 4];
            float4 wa = *(const float4*)&WaT[k][tx * 4];
            float4 wb = *(const float4*)&WbT[k][tx * 4];
            #pragma unroll
            for (int i = 0; i < 4; ++i)
                #pragma unroll
                for (int j = 0; j < 4; ++j) {
                    aa[i][j] += (&xv.x)[i] * (&wa.x)[j];
                    ab[i][j] += (&xv.x)[i] * (&wb.x)[j];
                }
        }
    }
    #pragma unroll
    for (int i = 0; i < 4; ++i) {
        int n = n0 + ty * 4 + i;
        #pragma unroll
        for (int j = 0; j < 4; ++j) {
            int o = o0 + tx * 4 + j;
            size_t off = ((size_t)b * N_PTS + n) * O + o;
            YaT[off] = aa[i][j];
            ZT[off] = ab[i][j] - aa[i][j] + bias[o];
        }
    }
}

// ---------------- out[n,o] = max_k lrelu(YaT[idx[n,k],o] + ZT[n,o], 0.2) ----------------
template<int O, int STAGE>
__global__ __launch_bounds__(256) void edge_reduce_kernel(const float* __restrict__ YaT,
                                                          const float* __restrict__ ZT,
                                                          const int* __restrict__ IDX,
                                                          float* __restrict__ CATp, int coloff) {
    int b = blockIdx.y;
    int tid = threadIdx.x;
    int n = blockIdx.x * (256 / O) + tid / O;
    int o = tid & (O - 1);
    const float* Ya_b = YaT + (size_t)b * N_PTS * O;
    float z = ZT[((size_t)b * N_PTS + n) * O + o];
    const int* ir = IDX + ((size_t)b * N_PTS + n) * KNN;
    float acc = -3.4e38f;
    #pragma unroll 8
    for (int k = 0; k < KNN; ++k) {
        int m = ir[k];
        float v = Ya_b[(size_t)m * O + o] + z;
        acc = fmaxf(acc, lrelu(v, 0.2f));
    }
    CATp[((size_t)b * N_PTS + n) * 512 + coloff + o] = acc;
}

// ---------------- g partials: lrelu(W5 @ cat + b5) with max over 64-row tile -------------
// 64(n) x 128(o) tile, acc[4][8], transposed conflict-free LDS
__global__ __launch_bounds__(256) void w5max_kernel(const float* __restrict__ CATp,
                                                    const float* __restrict__ W5,
                                                    const float* __restrict__ b5,
                                                    float* __restrict__ PART) {
    __shared__ float CsT[32][68];
    __shared__ float WsT[32][132];
    __shared__ float red[16][128];
    int b = blockIdx.z;
    int n0 = blockIdx.x * 64, o0 = blockIdx.y * 128;
    int tid = threadIdx.x, ty = tid >> 4, tx = tid & 15;
    const float* Cb = CATp + (size_t)b * N_PTS * 512;
    float acc[4][8] = {};
    for (int k0 = 0; k0 < 512; k0 += 32) {
        __syncthreads();
        for (int i = tid; i < 64 * 32; i += 256) {
            int r = i >> 5, c = i & 31;
            CsT[c][r] = Cb[(size_t)(n0 + r) * 512 + k0 + c];
        }
        for (int i = tid; i < 128 * 32; i += 256) {
            int r = i >> 5, c = i & 31;
            WsT[c][r] = W5[(size_t)(o0 + r) * 512 + k0 + c];
        }
        __syncthreads();
        #pragma unroll
        for (int k = 0; k < 32; ++k) {
            float4 a  = *(const float4*)&CsT[k][ty * 4];
            float4 w0 = *(const float4*)&WsT[k][tx * 8];
            float4 w1 = *(const float4*)&WsT[k][tx * 8 + 4];
            #pragma unroll
            for (int i = 0; i < 4; ++i) {
                float av = (&a.x)[i];
                #pragma unroll
                for (int j = 0; j < 4; ++j) {
                    acc[i][j]     += av * (&w0.x)[j];
                    acc[i][j + 4] += av * (&w1.x)[j];
                }
            }
        }
    }
    #pragma unroll
    for (int j = 0; j < 8; ++j) {
        int o = o0 + tx * 8 + j;
        float bo = b5[o];
        float m = -3.4e38f;
        #pragma unroll
        for (int i = 0; i < 4; ++i) m = fmaxf(m, lrelu(acc[i][j] + bo, 0.2f));
        red[ty][tx * 8 + j] = m;
    }
    __syncthreads();
    if (tid < 128) {
        float m = red[0][tid];
        #pragma unroll
        for (int t = 1; t < 16; ++t) m = fmaxf(m, red[t][tid]);
        PART[((size_t)b * 32 + blockIdx.x) * 1024 + o0 + tid] = m;
    }
}

__global__ void greduce_kernel(const float* __restrict__ PART, float* __restrict__ G) {
    int t = blockIdx.x * 256 + threadIdx.x;
    if (t >= BATCH * 1024) return;
    int b = t >> 10, o = t & 1023;
    const float* p = PART + (size_t)b * 32 * 1024 + o;
    float m = -3.4e38f;
    for (int nb = 0; nb < 32; ++nb) m = fmaxf(m, p[(size_t)nb * 1024]);
    G[t] = m;
}

// ---------------- FC: D0[b,j] = lrelu(g[b,:] . Wfc[j,:] + bfc[j]) ----------------
__global__ __launch_bounds__(256) void fc_kernel(const float* __restrict__ G,
                                                 const float* __restrict__ Wfc,
                                                 const float* __restrict__ bfc,
                                                 float* __restrict__ D0) {
    __shared__ float gl[2][1024];
    int tid = threadIdx.x;
    for (int i = tid; i < 2048; i += 256) gl[i >> 10][i & 1023] = G[i];
    __syncthreads();
    int wave = tid >> 6, lane = tid & 63;
    int j = blockIdx.x * 4 + wave;
    const float* wr = Wfc + (size_t)j * 1024;
    float a0 = 0.f, a1 = 0.f;
    for (int i = lane; i < 1024; i += 64) {
        float w = wr[i];
        a0 += w * gl[0][i];
        a1 += w * gl[1][i];
    }
    #pragma unroll
    for (int off = 32; off; off >>= 1) { a0 += __shfl_xor(a0, off); a1 += __shfl_xor(a1, off); }
    if (lane == 0) {
        float bb = bfc[j];
        D0[j] = lrelu(a0 + bb, 0.2f);
        D0[16384 + j] = lrelu(a1 + bb, 0.2f);
    }
}

// ---------------- fused up2 + conv3x3 (+ optional lrelu 0.2) ----------------
__global__ void upconv_kernel(const float* __restrict__ in, const float* __restrict__ W,
                              const float* __restrict__ bias, float* __restrict__ out,
                              int Ci, int Co, int Hi, int Wi, int total, int doRelu) {
    int t = blockIdx.x * 256 + threadIdx.x;
    if (t >= total) return;
    int Ho = Hi * 2, Wo = Wi * 2;
    int xo = t % Wo;
    int yo = (t / Wo) % Ho;
    int co = (t / (Wo * Ho)) % Co;
    int b = t / (Wo * Ho * Co);
    float acc = bias[co];
    const float* inb = in + (size_t)b * Ci * Hi * Wi;
    const float* wco = W + (size_t)co * Ci * 9;
    for (int ci = 0; ci < Ci; ++ci) {
        const float* ip = inb + (size_t)ci * Hi * Wi;
        const float* wp = wco + ci * 9;
        #pragma unroll
        for (int dy = 0; dy < 3; ++dy) {
            int yy = yo + dy - 1;
            if (yy < 0 || yy >= Ho) continue;
            const float* row = ip + (size_t)(yy >> 1) * Wi;
            #pragma unroll
            for (int dx = 0; dx < 3; ++dx) {
                int xx = xo + dx - 1;
                if (xx < 0 || xx >= Wo) continue;
                acc += row[xx >> 1] * wp[dy * 3 + dx];
            }
        }
    }
    if (doRelu) acc = lrelu(acc, 0.2f);
    out[t] = acc;
}

extern "C" void kernel_launch(void* const* d_in, const int* in_sizes, int n_in,
                              void* d_out, int out_size, void* d_ws, size_t ws_size,
                              hipStream_t stream) {
    const float* x   = (const float*)d_in[0];
    const float* Wc  = (const float*)d_in[1];
    const float* bc  = (const float*)d_in[2];
    const float* W1  = (const float*)d_in[3];
    const float* b1  = (const float*)d_in[4];
    const float* W2  = (const float*)d_in[5];
    const float* b2  = (const float*)d_in[6];
    const float* W3  = (const float*)d_in[7];
    const float* b3  = (const float*)d_in[8];
    const float* W4  = (const float*)d_in[9];
    const float* b4  = (const float*)d_in[10];
    const float* W5  = (const float*)d_in[11];
    const float* b5  = (const float*)d_in[12];
    const float* Wfc = (const float*)d_in[13];
    const float* bfc = (const float*)d_in[14];
    const float* Wd1 = (const float*)d_in[15];
    const float* bd1 = (const float*)d_in[16];
    const float* Wd2 = (const float*)d_in[17];
    const float* bd2 = (const float*)d_in[18];
    const float* Wd3 = (const float*)d_in[19];
    const float* bd3 = (const float*)d_in[20];
    float* out = (float*)d_out;

    char* ws = (char*)d_ws;
    float* Hb   = (float*)(ws + 0);          // (B,N,2)      32 KB
    float* CAT  = (float*)(ws + 32768);      // (B,N,512)    8 MB
    float* YaT  = (float*)(ws + 8421376);    // (B,N,256)    4 MB
    float* ZT   = (float*)(ws + 12615680);   // (B,N,256)    4 MB
    float* NEGD = (float*)(ws + 16809984);   // (N,N)        16 MB (reused per batch)
    float* XX   = (float*)(ws + 33587200);   // (B,N)
    int*   IDX  = (int*)  (ws + 33603584);   // (B,N,40)
    float* PART = (float*)(ws + 34258944);   // (B,32,1024)
    float* G    = (float*)(ws + 34521088);   // (B,1024)
    float* D0   = (float*)(ws + 34529280);   // (B,16384)
    float* DEC1 = (float*)(ws + 34660352);   // (B,32,32,32)
    float* DEC2 = (float*)(ws + 34922496);   // (B,16,64,64)

    prefix_kernel<<<16, 256, 0, stream>>>(x, Wc, bc, Hb);

    // ---- stage 1: C=2, O=64 ----
    xx_kernel<<<16, 256, 0, stream>>>(Hb, 2, (long)N_PTS * 2, 2, XX);
    for (int b = 0; b < BATCH; ++b) {
        gram_kernel<2, 1><<<dim3(32, 32), 256, 0, stream>>>(Hb + (size_t)b * N_PTS * 2, 2,
                                                            XX + b * N_PTS, NEGD);
        topk_kernel<1><<<N_PTS, 256, 0, stream>>>(NEGD, IDX + (size_t)b * N_PTS * KNN);
    }
    ya_z_kernel<2, 64, 1><<<dim3(32, 1, BATCH), 256, 0, stream>>>(Hb, 2, (long)N_PTS * 2,
                                                                  W1, b1, YaT, ZT);
    edge_reduce_kernel<64, 1><<<dim3(N_PTS * 64 / 256, BATCH), 256, 0, stream>>>(YaT, ZT, IDX,
                                                                                 CAT, 0);
    // ---- stage 2: C=64, O=64 ----
    xx_kernel<<<16, 256, 0, stream>>>(CAT + 0, 512, (long)N_PTS * 512, 64, XX);
    for (int b = 0; b < BATCH; ++b) {
        gram_kernel<64, 2><<<dim3(32, 32), 256, 0, stream>>>(CAT + 0 + (size_t)b * N_PTS * 512,
                                                             512, XX + b * N_PTS, NEGD);
        topk_kernel<2><<<N_PTS, 256, 0, stream>>>(NEGD, IDX + (size_t)b * N_PTS * KNN);
    }
    ya_z_kernel<64, 64, 2><<<dim3(32, 1, BATCH), 256, 0, stream>>>(CAT + 0, 512,
                                                                   (long)N_PTS * 512,
                                                                   W2, b2, YaT, ZT);
    edge_reduce_kernel<64, 2><<<dim3(N_PTS * 64 / 256, BATCH), 256, 0, stream>>>(YaT, ZT, IDX,
                                                                                 CAT, 64);
    // ---- stage 3: C=64, O=128 ----
    xx_kernel<<<16, 256, 0, stream>>>(CAT + 64, 512, (long)N_PTS * 512, 64, XX);
    for (int b = 0; b < BATCH; ++b) {
        gram_kernel<64, 3><<<dim3(32, 32), 256, 0, stream>>>(CAT + 64 + (size_t)b * N_PTS * 512,
                                                             512, XX + b * N_PTS, NEGD);
        topk_kernel<3><<<N_PTS, 256, 0, stream>>>(NEGD, IDX + (size_t)b * N_PTS * KNN);
    }
    ya_z_kernel<64, 128, 3><<<dim3(32, 2, BATCH), 256, 0, stream>>>(CAT + 64, 512,
                                                                    (long)N_PTS * 512,
                                                                    W3, b3, YaT, ZT);
    edge_reduce_kernel<128, 3><<<dim3(N_PTS * 128 / 256, BATCH), 256, 0, stream>>>(YaT, ZT, IDX,
                                                                                   CAT, 128);
    // ---- stage 4: C=128, O=256 ----
    xx_kernel<<<16, 256, 0, stream>>>(CAT + 128, 512, (long)N_PTS * 512, 128, XX);
    for (int b = 0; b < BATCH; ++b) {
        gram_kernel<128, 4><<<dim3(32, 32), 256, 0, stream>>>(CAT + 128 + (size_t)b * N_PTS * 512,
                                                              512, XX + b * N_PTS, NEGD);
        topk_kernel<4><<<N_PTS, 256, 0, stream>>>(NEGD, IDX + (size_t)b * N_PTS * KNN);
    }
    ya_z_kernel<128, 256, 4><<<dim3(32, 4, BATCH), 256, 0, stream>>>(CAT + 128, 512,
                                                                     (long)N_PTS * 512,
                                                                     W4, b4, YaT, ZT);
    edge_reduce_kernel<256, 4><<<dim3(N_PTS * 256 / 256, BATCH), 256, 0, stream>>>(YaT, ZT, IDX,
                                                                                   CAT, 256);

    w5max_kernel<<<dim3(32, 8, BATCH), 256, 0, stream>>>(CAT, W5, b5, PART);
    greduce_kernel<<<8, 256, 0, stream>>>(PART, G);
    fc_kernel<<<4096, 256, 0, stream>>>(G, Wfc, bfc, D0);

    upconv_kernel<<<(2 * 32 * 32 * 32 + 255) / 256, 256, 0, stream>>>(D0, Wd1, bd1, DEC1,
                                                                      64, 32, 16, 16,
                                                                      2 * 32 * 32 * 32, 1);
    upconv_kernel<<<(2 * 16 * 64 * 64 + 255) / 256, 256, 0, stream>>>(DEC1, Wd2, bd2, DEC2,
                                                                      32, 16, 32, 32,
                                                                      2 * 16 * 64 * 64, 1);
    upconv_kernel<<<(2 * 1 * 128 * 128 + 255) / 256, 256, 0, stream>>>(DEC2, Wd3, bd3, out,
                                                                       16, 1, 64, 64,
                                                                       2 * 1 * 128 * 128, 0);
}

// Round 3
// 737.099 us; speedup vs baseline: 2.8315x; 1.0239x over previous
//
#include <hip/hip_runtime.h>
#include <hip/hip_bf16.h>

#define N_PTS 2048
#define BATCH 2
#define KNN 40

typedef __attribute__((ext_vector_type(8))) short bf16x8;
typedef __attribute__((ext_vector_type(16))) float f32x16;

__device__ __forceinline__ float lrelu(float v, float s) {
    return v >= 0.f ? v : s * v;
}

// ---------------- prefix: conv (5,3)/(5,1) + lrelu(0.01) -> H (B,N,2) ----------------
__global__ void prefix_kernel(const float* __restrict__ x, const float* __restrict__ Wc,
                              const float* __restrict__ bc, float* __restrict__ H) {
    int t = blockIdx.x * 256 + threadIdx.x;
    if (t >= BATCH * N_PTS) return;
    int b = t >> 11, n = t & 2047;
    #pragma unroll
    for (int oh = 0; oh < 2; ++oh) {
        float acc = bc[0];
        #pragma unroll
        for (int kh = 0; kh < 5; ++kh) {
            const float* xr = x + ((size_t)b * 10 + oh * 5 + kh) * N_PTS;
            #pragma unroll
            for (int kw = 0; kw < 3; ++kw) {
                int nn = n + kw - 1;
                if (nn >= 0 && nn < N_PTS) acc += xr[nn] * Wc[kh * 3 + kw];
            }
        }
        H[(size_t)t * 2 + oh] = lrelu(acc, 0.01f);
    }
}

// ---------------- xx[b,n] = sum_c X[b,n,c]^2 ----------------
__global__ void xx_kernel(const float* __restrict__ X, int S, long bsX, int C,
                          float* __restrict__ XX) {
    int t = blockIdx.x * 256 + threadIdx.x;
    if (t >= BATCH * N_PTS) return;
    int b = t >> 11, n = t & 2047;
    const float* row = X + (size_t)b * bsX + (size_t)n * S;
    float s = 0.f;
    for (int c = 0; c < C; ++c) { float v = row[c]; s += v * v; }
    XX[t] = s;
}

// ---------------- gram small (C=2, stage 1): 64x64 tile, 4x4/thread ----------------
__global__ __launch_bounds__(256) void gram_small_kernel(const float* __restrict__ X,
                                                         const float* __restrict__ xx,
                                                         float* __restrict__ negd) {
    __shared__ float AsT[2][68];
    __shared__ float BsT[2][68];
    int tid = threadIdx.x;
    int r0 = blockIdx.y * 64, c0 = blockIdx.x * 64;
    int ty = tid >> 4, tx = tid & 15;
    float acc[4][4] = {};
    if (tid < 128) {
        int r = tid >> 1, c = tid & 1;
        AsT[c][r] = X[(size_t)(r0 + r) * 2 + c];
        BsT[c][r] = X[(size_t)(c0 + r) * 2 + c];
    }
    __syncthreads();
    #pragma unroll
    for (int k = 0; k < 2; ++k) {
        float4 a = *(const float4*)&AsT[k][ty * 4];
        float4 b = *(const float4*)&BsT[k][tx * 4];
        #pragma unroll
        for (int i = 0; i < 4; ++i)
            #pragma unroll
            for (int j = 0; j < 4; ++j)
                acc[i][j] += (&a.x)[i] * (&b.x)[j];
    }
    #pragma unroll
    for (int i = 0; i < 4; ++i) {
        int r = r0 + ty * 4 + i;
        float xr = xx[r];
        #pragma unroll
        for (int j = 0; j < 4; ++j) {
            int c = c0 + tx * 4 + j;
            negd[(size_t)r * N_PTS + c] = 2.0f * acc[i][j] - xr - xx[c];
        }
    }
}

// ---------------- gram big (C=64/128): 128x128 tile, 8x8/thread, split-col map ----------
template<int C, int STAGE>
__global__ __launch_bounds__(256) void gram_kernel(const float* __restrict__ X, int S,
                                                   const float* __restrict__ xx,
                                                   float* __restrict__ negd) {
    __shared__ float AsT[32][132];
    __shared__ float BsT[32][132];
    int tid = threadIdx.x;
    int r0 = blockIdx.y * 128, c0 = blockIdx.x * 128;
    int ty = tid >> 4, tx = tid & 15;
    float acc[8][8] = {};
    for (int k0 = 0; k0 < C; k0 += 32) {
        __syncthreads();
        #pragma unroll
        for (int p = 0; p < 16; ++p) {
            int i = tid + p * 256;
            int c = i & 31, rw = i >> 5;
            AsT[c][rw] = X[(size_t)(r0 + rw) * S + k0 + c];
            BsT[c][rw] = X[(size_t)(c0 + rw) * S + k0 + c];
        }
        __syncthreads();
        #pragma unroll 8
        for (int k = 0; k < 32; ++k) {
            float4 a0 = *(const float4*)&AsT[k][ty * 4];
            float4 a1 = *(const float4*)&AsT[k][64 + ty * 4];
            float4 b0 = *(const float4*)&BsT[k][tx * 4];
            float4 b1 = *(const float4*)&BsT[k][64 + tx * 4];
            #pragma unroll
            for (int i = 0; i < 4; ++i) {
                float av0 = (&a0.x)[i], av1 = (&a1.x)[i];
                #pragma unroll
                for (int j = 0; j < 4; ++j) {
                    float bv0 = (&b0.x)[j], bv1 = (&b1.x)[j];
                    acc[i][j]         += av0 * bv0;
                    acc[i][j + 4]     += av0 * bv1;
                    acc[i + 4][j]     += av1 * bv0;
                    acc[i + 4][j + 4] += av1 * bv1;
                }
            }
        }
    }
    float xc0[4], xc1[4];
    #pragma unroll
    for (int j = 0; j < 4; ++j) {
        xc0[j] = xx[c0 + tx * 4 + j];
        xc1[j] = xx[c0 + 64 + tx * 4 + j];
    }
    #pragma unroll
    for (int i = 0; i < 8; ++i) {
        int r = r0 + (i < 4 ? ty * 4 + i : 64 + ty * 4 + (i - 4));
        float xr = xx[r];
        float4 o0v, o1v;
        #pragma unroll
        for (int j = 0; j < 4; ++j) {
            (&o0v.x)[j] = 2.0f * acc[i][j] - xr - xc0[j];
            (&o1v.x)[j] = 2.0f * acc[i][j + 4] - xr - xc1[j];
        }
        *(float4*)&negd[(size_t)r * N_PTS + c0 + tx * 4] = o0v;
        *(float4*)&negd[(size_t)r * N_PTS + c0 + 64 + tx * 4] = o1v;
    }
}

// ---------------- top-40 per row: 3-round radix select, wave-scan version ----------------
template<int STAGE>
__global__ __launch_bounds__(256) void topk_kernel(const float* __restrict__ negd,
                                                   int* __restrict__ idx_out) {
    __shared__ unsigned keys[N_PTS];
    __shared__ unsigned hist[4096];
    __shared__ unsigned wsum[4];
    __shared__ unsigned sc[4];
    int n = blockIdx.x;
    int tid = threadIdx.x;
    int wave = tid >> 6, lane = tid & 63;
    const float* row = negd + (size_t)n * N_PTS;
    for (int i = tid; i < 4096; i += 256) hist[i] = 0u;
    __syncthreads();
    for (int j = tid; j < N_PTS; j += 256) {
        unsigned u = __float_as_uint(row[j]);
        u = (u & 0x80000000u) ? ~u : (u | 0x80000000u);
        keys[j] = u;
        atomicAdd(&hist[u >> 20], 1u);
    }
    __syncthreads();
    unsigned r = KNN;
    // ---- round 1: bits [31:20] ----
    {
        unsigned chunk = 0;
        #pragma unroll
        for (int q = 0; q < 16; ++q) chunk += hist[tid * 16 + q];
        unsigned s = chunk;
        #pragma unroll
        for (int off = 1; off < 64; off <<= 1) {
            unsigned v = __shfl_down(s, off);
            if (lane + off < 64) s += v;
        }
        if (lane == 0) wsum[wave] = s;
        __syncthreads();
        unsigned add = 0;
        for (int w = wave + 1; w < 4; ++w) add += wsum[w];
        unsigned St = s + add, Sn = St - chunk;
        if (St >= r && Sn < r) { sc[0] = (unsigned)tid; sc[1] = r - Sn; }
        __syncthreads();
        if (tid == 0) {
            int c = (int)sc[0]; unsigned rc = sc[1];
            unsigned cum = 0; int b = c * 16 + 15;
            for (;; --b) { cum += hist[b]; if (cum >= rc) break; }
            sc[0] = (unsigned)b; sc[1] = rc - (cum - hist[b]);
        }
        __syncthreads();
    }
    unsigned p1 = sc[0]; r = sc[1];
    __syncthreads();
    // ---- round 2: bits [19:8] among prefix==p1 ----
    for (int i = tid; i < 4096; i += 256) hist[i] = 0u;
    __syncthreads();
    for (int j = tid; j < N_PTS; j += 256)
        if ((keys[j] >> 20) == p1) atomicAdd(&hist[(keys[j] >> 8) & 0xFFFu], 1u);
    __syncthreads();
    {
        unsigned chunk = 0;
        #pragma unroll
        for (int q = 0; q < 16; ++q) chunk += hist[tid * 16 + q];
        unsigned s = chunk;
        #pragma unroll
        for (int off = 1; off < 64; off <<= 1) {
            unsigned v = __shfl_down(s, off);
            if (lane + off < 64) s += v;
        }
        if (lane == 0) wsum[wave] = s;
        __syncthreads();
        unsigned add = 0;
        for (int w = wave + 1; w < 4; ++w) add += wsum[w];
        unsigned St = s + add, Sn = St - chunk;
        if (St >= r && Sn < r) { sc[0] = (unsigned)tid; sc[1] = r - Sn; }
        __syncthreads();
        if (tid == 0) {
            int c = (int)sc[0]; unsigned rc = sc[1];
            unsigned cum = 0; int b = c * 16 + 15;
            for (;; --b) { cum += hist[b]; if (cum >= rc) break; }
            sc[0] = (unsigned)b; sc[1] = rc - (cum - hist[b]);
        }
        __syncthreads();
    }
    unsigned p2 = (p1 << 12) | sc[0]; r = sc[1];
    __syncthreads();
    // ---- round 3: bits [7:0] among prefix==p2 (1 bin/thread) ----
    hist[tid] = 0u;
    __syncthreads();
    for (int j = tid; j < N_PTS; j += 256)
        if ((keys[j] >> 8) == p2) atomicAdd(&hist[keys[j] & 0xFFu], 1u);
    __syncthreads();
    {
        unsigned chunk = hist[tid];
        unsigned s = chunk;
        #pragma unroll
        for (int off = 1; off < 64; off <<= 1) {
            unsigned v = __shfl_down(s, off);
            if (lane + off < 64) s += v;
        }
        if (lane == 0) wsum[wave] = s;
        __syncthreads();
        unsigned add = 0;
        for (int w = wave + 1; w < 4; ++w) add += wsum[w];
        unsigned St = s + add, Sn = St - chunk;
        if (St >= r && Sn < r) { sc[0] = (unsigned)tid; sc[1] = r - Sn; }
        __syncthreads();
    }
    unsigned T = (p2 << 8) | sc[0];
    unsigned r3 = sc[1];
    // ---- collect strictly-greater ----
    if (tid == 0) sc[2] = 0u;
    __syncthreads();
    int* out = idx_out + (size_t)n * KNN;
    for (int j = tid; j < N_PTS; j += 256)
        if (keys[j] > T) out[atomicAdd(&sc[2], 1u)] = j;
    __syncthreads();
    // ---- ties at T: take r3 lowest indices (matches lax.top_k stability) ----
    int last = -1;
    for (unsigned t = 0; t < r3; ++t) {
        unsigned m = 0xFFFFFFFFu;
        for (int j = tid; j < N_PTS; j += 256)
            if (keys[j] == T && j > last) { m = (unsigned)j; break; }
        hist[tid] = m;
        __syncthreads();
        for (int st = 128; st >= 1; st >>= 1) {
            if (tid < st) hist[tid] = min(hist[tid], hist[tid + st]);
            __syncthreads();
        }
        if (tid == 0) { out[KNN - (int)r3 + (int)t] = (int)hist[0]; sc[3] = hist[0]; }
        __syncthreads();
        last = (int)sc[3];
    }
}

// ---------------- YaT = X @ Wa^T ; ZT = X @ Wb^T - YaT + bias  (layout (B,N,O)) ---------
template<int C, int O, int STAGE>
__global__ __launch_bounds__(256) void ya_z_kernel(const float* __restrict__ X, int S, long bsX,
                                                   const float* __restrict__ W,
                                                   const float* __restrict__ bias,
                                                   float* __restrict__ YaT, float* __restrict__ ZT) {
    constexpr int KC = (C < 32) ? C : 32;
    __shared__ float XsT[KC][68];
    __shared__ float WaT[KC][68];
    __shared__ float WbT[KC][68];
    int b = blockIdx.z;
    const float* Xb = X + (size_t)b * bsX;
    int n0 = blockIdx.x * 64, o0 = blockIdx.y * 64;
    int tid = threadIdx.x, ty = tid >> 4, tx = tid & 15;
    float aa[4][4] = {}, ab[4][4] = {};
    for (int k0 = 0; k0 < C; k0 += KC) {
        __syncthreads();
        for (int i = tid; i < 64 * KC; i += 256) {
            int r = i / KC, c = i % KC;
            XsT[c][r] = Xb[(size_t)(n0 + r) * S + k0 + c];
            WaT[c][r] = W[(size_t)(o0 + r) * 2 * C + k0 + c];
            WbT[c][r] = W[(size_t)(o0 + r) * 2 * C + C + k0 + c];
        }
        __syncthreads();
        #pragma unroll
        for (int k = 0; k < KC; ++k) {
            float4 xv = *(const float4*)&XsT[k][ty * 4];
            float4 wa = *(const float4*)&WaT[k][tx * 4];
            float4 wb = *(const float4*)&WbT[k][tx * 4];
            #pragma unroll
            for (int i = 0; i < 4; ++i)
                #pragma unroll
                for (int j = 0; j < 4; ++j) {
                    aa[i][j] += (&xv.x)[i] * (&wa.x)[j];
                    ab[i][j] += (&xv.x)[i] * (&wb.x)[j];
                }
        }
    }
    #pragma unroll
    for (int i = 0; i < 4; ++i) {
        int n = n0 + ty * 4 + i;
        #pragma unroll
        for (int j = 0; j < 4; ++j) {
            int o = o0 + tx * 4 + j;
            size_t off = ((size_t)b * N_PTS + n) * O + o;
            YaT[off] = aa[i][j];
            ZT[off] = ab[i][j] - aa[i][j] + bias[o];
        }
    }
}

// ---------------- out[n,o] = max_k lrelu(YaT[idx[n,k],o] + ZT[n,o], 0.2) ----------------
template<int O, int STAGE>
__global__ __launch_bounds__(256) void edge_reduce_kernel(const float* __restrict__ YaT,
                                                          const float* __restrict__ ZT,
                                                          const int* __restrict__ IDX,
                                                          float* __restrict__ CATp, int coloff) {
    int b = blockIdx.y;
    int tid = threadIdx.x;
    int n = blockIdx.x * (256 / O) + tid / O;
    int o = tid & (O - 1);
    const float* Ya_b = YaT + (size_t)b * N_PTS * O;
    float z = ZT[((size_t)b * N_PTS + n) * O + o];
    const int* ir = IDX + ((size_t)b * N_PTS + n) * KNN;
    float acc = -3.4e38f;
    #pragma unroll 8
    for (int k = 0; k < KNN; ++k) {
        int m = ir[k];
        float v = Ya_b[(size_t)m * O + o] + z;
        acc = fmaxf(acc, lrelu(v, 0.2f));
    }
    CATp[((size_t)b * N_PTS + n) * 512 + coloff + o] = acc;
}

// ---------------- fp32 -> bf16 hi/lo split ----------------
__global__ void cvt_split_kernel(const float* __restrict__ src, short* __restrict__ hi,
                                 short* __restrict__ lo, int total4) {
    int t = blockIdx.x * 256 + threadIdx.x;
    if (t >= total4) return;
    float4 v = ((const float4*)src)[t];
    short4 h, l;
    #pragma unroll
    for (int j = 0; j < 4; ++j) {
        float x = (&v.x)[j];
        __hip_bfloat16 hb = __float2bfloat16(x);
        float hf = __bfloat162float(hb);
        __hip_bfloat16 lb = __float2bfloat16(x - hf);
        (&h.x)[j] = *reinterpret_cast<short*>(&hb);
        (&l.x)[j] = *reinterpret_cast<short*>(&lb);
    }
    ((short4*)hi)[t] = h;
    ((short4*)lo)[t] = l;
}

// ---------------- w5max: split-bf16 3-pass MFMA, L2-direct, no LDS staging --------------
// PART[b][mblk][o] = max over 128 rows of lrelu(CAT @ W5^T + b5)
__global__ __launch_bounds__(256) void w5max_mfma_kernel(
        const short* __restrict__ Ah, const short* __restrict__ Al,
        const short* __restrict__ Bh, const short* __restrict__ Bl,
        const float* __restrict__ b5, float* __restrict__ PART) {
    __shared__ float red[2][128];
    int b = blockIdx.z;
    int tid = threadIdx.x;
    int wave = tid >> 6, lane = tid & 63;
    int wm = wave >> 1, wn = wave & 1;
    int m0 = blockIdx.x * 128 + wm * 64;
    int o0 = blockIdx.y * 128 + wn * 64;
    int rr = lane & 31;
    int kg = lane >> 5;
    const int FS = 32 * 512;
    const short* pAh = Ah + ((size_t)b * N_PTS + m0 + rr) * 512 + kg * 8;
    const short* pAl = Al + ((size_t)b * N_PTS + m0 + rr) * 512 + kg * 8;
    const short* pBh = Bh + (size_t)(o0 + rr) * 512 + kg * 8;
    const short* pBl = Bl + (size_t)(o0 + rr) * 512 + kg * 8;
    f32x16 a00 = {}, a01 = {}, a10 = {}, a11 = {};
    bf16x8 ah0 = *(const bf16x8*)(pAh);
    bf16x8 ah1 = *(const bf16x8*)(pAh + FS);
    bf16x8 al0 = *(const bf16x8*)(pAl);
    bf16x8 al1 = *(const bf16x8*)(pAl + FS);
    bf16x8 bh0 = *(const bf16x8*)(pBh);
    bf16x8 bh1 = *(const bf16x8*)(pBh + FS);
    bf16x8 bl0 = *(const bf16x8*)(pBl);
    bf16x8 bl1 = *(const bf16x8*)(pBl + FS);
    #pragma unroll 2
    for (int kc = 0; kc < 32; ++kc) {
        int kn = ((kc + 1) & 31) * 16;
        bf16x8 nah0 = *(const bf16x8*)(pAh + kn);
        bf16x8 nah1 = *(const bf16x8*)(pAh + kn + FS);
        bf16x8 nal0 = *(const bf16x8*)(pAl + kn);
        bf16x8 nal1 = *(const bf16x8*)(pAl + kn + FS);
        bf16x8 nbh0 = *(const bf16x8*)(pBh + kn);
        bf16x8 nbh1 = *(const bf16x8*)(pBh + kn + FS);
        bf16x8 nbl0 = *(const bf16x8*)(pBl + kn);
        bf16x8 nbl1 = *(const bf16x8*)(pBl + kn + FS);
        a00 = __builtin_amdgcn_mfma_f32_32x32x16_bf16(ah0, bh0, a00, 0, 0, 0);
        a00 = __builtin_amdgcn_mfma_f32_32x32x16_bf16(ah0, bl0, a00, 0, 0, 0);
        a00 = __builtin_amdgcn_mfma_f32_32x32x16_bf16(al0, bh0, a00, 0, 0, 0);
        a01 = __builtin_amdgcn_mfma_f32_32x32x16_bf16(ah0, bh1, a01, 0, 0, 0);
        a01 = __builtin_amdgcn_mfma_f32_32x32x16_bf16(ah0, bl1, a01, 0, 0, 0);
        a01 = __builtin_amdgcn_mfma_f32_32x32x16_bf16(al0, bh1, a01, 0, 0, 0);
        a10 = __builtin_amdgcn_mfma_f32_32x32x16_bf16(ah1, bh0, a10, 0, 0, 0);
        a10 = __builtin_amdgcn_mfma_f32_32x32x16_bf16(ah1, bl0, a10, 0, 0, 0);
        a10 = __builtin_amdgcn_mfma_f32_32x32x16_bf16(al1, bh0, a10, 0, 0, 0);
        a11 = __builtin_amdgcn_mfma_f32_32x32x16_bf16(ah1, bh1, a11, 0, 0, 0);
        a11 = __builtin_amdgcn_mfma_f32_32x32x16_bf16(ah1, bl1, a11, 0, 0, 0);
        a11 = __builtin_amdgcn_mfma_f32_32x32x16_bf16(al1, bh1, a11, 0, 0, 0);
        ah0 = nah0; ah1 = nah1; al0 = nal0; al1 = nal1;
        bh0 = nbh0; bh1 = nbh1; bl0 = nbl0; bl1 = nbl1;
    }
    #pragma unroll
    for (int fn = 0; fn < 2; ++fn) {
        float bo = b5[o0 + fn * 32 + rr];
        float m = -3.4e38f;
        #pragma unroll
        for (int r = 0; r < 16; ++r) {
            float v0 = (fn == 0) ? a00[r] : a01[r];
            float v1 = (fn == 0) ? a10[r] : a11[r];
            m = fmaxf(m, lrelu(v0 + bo, 0.2f));
            m = fmaxf(m, lrelu(v1 + bo, 0.2f));
        }
        m = fmaxf(m, __shfl_xor(m, 32));
        red[wm][wn * 64 + fn * 32 + rr] = m;
    }
    __syncthreads();
    if (tid < 128)
        PART[((size_t)b * 16 + blockIdx.x) * 1024 + blockIdx.y * 128 + tid] =
            fmaxf(red[0][tid], red[1][tid]);
}

__global__ void greduce_kernel(const float* __restrict__ PART, float* __restrict__ G) {
    int t = blockIdx.x * 256 + threadIdx.x;
    if (t >= BATCH * 1024) return;
    int b = t >> 10, o = t & 1023;
    const float* p = PART + (size_t)b * 16 * 1024 + o;
    float m = -3.4e38f;
    for (int nb = 0; nb < 16; ++nb) m = fmaxf(m, p[(size_t)nb * 1024]);
    G[t] = m;
}

// ---------------- FC: D0[b,j] = lrelu(g[b,:] . Wfc[j,:] + bfc[j]) ----------------
__global__ __launch_bounds__(256) void fc_kernel(const float* __restrict__ G,
                                                 const float* __restrict__ Wfc,
                                                 const float* __restrict__ bfc,
                                                 float* __restrict__ D0) {
    __shared__ float gl[2][1024];
    int tid = threadIdx.x;
    for (int i = tid; i < 2048; i += 256) gl[i >> 10][i & 1023] = G[i];
    __syncthreads();
    int wave = tid >> 6, lane = tid & 63;
    int j = blockIdx.x * 4 + wave;
    const float* wr = Wfc + (size_t)j * 1024;
    float a0 = 0.f, a1 = 0.f;
    for (int i = lane; i < 1024; i += 64) {
        float w = wr[i];
        a0 += w * gl[0][i];
        a1 += w * gl[1][i];
    }
    #pragma unroll
    for (int off = 32; off; off >>= 1) { a0 += __shfl_xor(a0, off); a1 += __shfl_xor(a1, off); }
    if (lane == 0) {
        float bb = bfc[j];
        D0[j] = lrelu(a0 + bb, 0.2f);
        D0[16384 + j] = lrelu(a1 + bb, 0.2f);
    }
}

// ---------------- fused up2 + conv3x3 (+ optional lrelu 0.2) ----------------
__global__ void upconv_kernel(const float* __restrict__ in, const float* __restrict__ W,
                              const float* __restrict__ bias, float* __restrict__ out,
                              int Ci, int Co, int Hi, int Wi, int total, int doRelu) {
    int t = blockIdx.x * 256 + threadIdx.x;
    if (t >= total) return;
    int Ho = Hi * 2, Wo = Wi * 2;
    int xo = t % Wo;
    int yo = (t / Wo) % Ho;
    int co = (t / (Wo * Ho)) % Co;
    int b = t / (Wo * Ho * Co);
    float acc = bias[co];
    const float* inb = in + (size_t)b * Ci * Hi * Wi;
    const float* wco = W + (size_t)co * Ci * 9;
    for (int ci = 0; ci < Ci; ++ci) {
        const float* ip = inb + (size_t)ci * Hi * Wi;
        const float* wp = wco + ci * 9;
        #pragma unroll
        for (int dy = 0; dy < 3; ++dy) {
            int yy = yo + dy - 1;
            if (yy < 0 || yy >= Ho) continue;
            const float* row = ip + (size_t)(yy >> 1) * Wi;
            #pragma unroll
            for (int dx = 0; dx < 3; ++dx) {
                int xx = xo + dx - 1;
                if (xx < 0 || xx >= Wo) continue;
                acc += row[xx >> 1] * wp[dy * 3 + dx];
            }
        }
    }
    if (doRelu) acc = lrelu(acc, 0.2f);
    out[t] = acc;
}

extern "C" void kernel_launch(void* const* d_in, const int* in_sizes, int n_in,
                              void* d_out, int out_size, void* d_ws, size_t ws_size,
                              hipStream_t stream) {
    const float* x   = (const float*)d_in[0];
    const float* Wc  = (const float*)d_in[1];
    const float* bc  = (const float*)d_in[2];
    const float* W1  = (const float*)d_in[3];
    const float* b1  = (const float*)d_in[4];
    const float* W2  = (const float*)d_in[5];
    const float* b2  = (const float*)d_in[6];
    const float* W3  = (const float*)d_in[7];
    const float* b3  = (const float*)d_in[8];
    const float* W4  = (const float*)d_in[9];
    const float* b4  = (const float*)d_in[10];
    const float* W5  = (const float*)d_in[11];
    const float* b5  = (const float*)d_in[12];
    const float* Wfc = (const float*)d_in[13];
    const float* bfc = (const float*)d_in[14];
    const float* Wd1 = (const float*)d_in[15];
    const float* bd1 = (const float*)d_in[16];
    const float* Wd2 = (const float*)d_in[17];
    const float* bd2 = (const float*)d_in[18];
    const float* Wd3 = (const float*)d_in[19];
    const float* bd3 = (const float*)d_in[20];
    float* out = (float*)d_out;

    char* ws = (char*)d_ws;
    float* Hb   = (float*)(ws + 0);          // (B,N,2)
    float* CAT  = (float*)(ws + 32768);      // (B,N,512)    8 MB
    float* YaT  = (float*)(ws + 8421376);    // (B,N,256)    4 MB
    float* ZT   = (float*)(ws + 12615680);   // (B,N,256)    4 MB
    float* NEGD = (float*)(ws + 16809984);   // (N,N) 16 MB (reused per batch)
    // after all EdgeConv stages, the NEGD region is reused for bf16 splits:
    short* CATh = (short*)(ws + 16809984);   // (B,N,512) bf16  4 MB
    short* CATl = (short*)(ws + 21004288);   // 4 MB
    short* W5h  = (short*)(ws + 25198592);   // (1024,512) bf16 1 MB
    short* W5l  = (short*)(ws + 26247168);   // 1 MB
    float* XX   = (float*)(ws + 33587200);   // (B,N)
    int*   IDX  = (int*)  (ws + 33603584);   // (B,N,40)
    float* PART = (float*)(ws + 34258944);   // (B,16,1024)
    float* G    = (float*)(ws + 34521088);   // (B,1024)
    float* D0   = (float*)(ws + 34529280);   // (B,16384)
    float* DEC1 = (float*)(ws + 34660352);   // (B,32,32,32)
    float* DEC2 = (float*)(ws + 34922496);   // (B,16,64,64)

    prefix_kernel<<<16, 256, 0, stream>>>(x, Wc, bc, Hb);

    // ---- stage 1: C=2, O=64 ----
    xx_kernel<<<16, 256, 0, stream>>>(Hb, 2, (long)N_PTS * 2, 2, XX);
    for (int b = 0; b < BATCH; ++b) {
        gram_small_kernel<<<dim3(32, 32), 256, 0, stream>>>(Hb + (size_t)b * N_PTS * 2,
                                                            XX + b * N_PTS, NEGD);
        topk_kernel<1><<<N_PTS, 256, 0, stream>>>(NEGD, IDX + (size_t)b * N_PTS * KNN);
    }
    ya_z_kernel<2, 64, 1><<<dim3(32, 1, BATCH), 256, 0, stream>>>(Hb, 2, (long)N_PTS * 2,
                                                                  W1, b1, YaT, ZT);
    edge_reduce_kernel<64, 1><<<dim3(N_PTS * 64 / 256, BATCH), 256, 0, stream>>>(YaT, ZT, IDX,
                                                                                 CAT, 0);
    // ---- stage 2: C=64, O=64 ----
    xx_kernel<<<16, 256, 0, stream>>>(CAT + 0, 512, (long)N_PTS * 512, 64, XX);
    for (int b = 0; b < BATCH; ++b) {
        gram_kernel<64, 2><<<dim3(16, 16), 256, 0, stream>>>(CAT + 0 + (size_t)b * N_PTS * 512,
                                                             512, XX + b * N_PTS, NEGD);
        topk_kernel<2><<<N_PTS, 256, 0, stream>>>(NEGD, IDX + (size_t)b * N_PTS * KNN);
    }
    ya_z_kernel<64, 64, 2><<<dim3(32, 1, BATCH), 256, 0, stream>>>(CAT + 0, 512,
                                                                   (long)N_PTS * 512,
                                                                   W2, b2, YaT, ZT);
    edge_reduce_kernel<64, 2><<<dim3(N_PTS * 64 / 256, BATCH), 256, 0, stream>>>(YaT, ZT, IDX,
                                                                                 CAT, 64);
    // ---- stage 3: C=64, O=128 ----
    xx_kernel<<<16, 256, 0, stream>>>(CAT + 64, 512, (long)N_PTS * 512, 64, XX);
    for (int b = 0; b < BATCH; ++b) {
        gram_kernel<64, 3><<<dim3(16, 16), 256, 0, stream>>>(CAT + 64 + (size_t)b * N_PTS * 512,
                                                             512, XX + b * N_PTS, NEGD);
        topk_kernel<3><<<N_PTS, 256, 0, stream>>>(NEGD, IDX + (size_t)b * N_PTS * KNN);
    }
    ya_z_kernel<64, 128, 3><<<dim3(32, 2, BATCH), 256, 0, stream>>>(CAT + 64, 512,
                                                                    (long)N_PTS * 512,
                                                                    W3, b3, YaT, ZT);
    edge_reduce_kernel<128, 3><<<dim3(N_PTS * 128 / 256, BATCH), 256, 0, stream>>>(YaT, ZT, IDX,
                                                                                   CAT, 128);
    // ---- stage 4: C=128, O=256 ----
    xx_kernel<<<16, 256, 0, stream>>>(CAT + 128, 512, (long)N_PTS * 512, 128, XX);
    for (int b = 0; b < BATCH; ++b) {
        gram_kernel<128, 4><<<dim3(16, 16), 256, 0, stream>>>(CAT + 128 + (size_t)b * N_PTS * 512,
                                                              512, XX + b * N_PTS, NEGD);
        topk_kernel<4><<<N_PTS, 256, 0, stream>>>(NEGD, IDX + (size_t)b * N_PTS * KNN);
    }
    ya_z_kernel<128, 256, 4><<<dim3(32, 4, BATCH), 256, 0, stream>>>(CAT + 128, 512,
                                                                     (long)N_PTS * 512,
                                                                     W4, b4, YaT, ZT);
    edge_reduce_kernel<256, 4><<<dim3(N_PTS * 256 / 256, BATCH), 256, 0, stream>>>(YaT, ZT, IDX,
                                                                                   CAT, 256);

    // ---- global feature: split-bf16 MFMA W5 + max ----
    cvt_split_kernel<<<(BATCH * N_PTS * 512 / 4 + 255) / 256, 256, 0, stream>>>(
        CAT, CATh, CATl, BATCH * N_PTS * 512 / 4);
    cvt_split_kernel<<<(1024 * 512 / 4 + 255) / 256, 256, 0, stream>>>(
        W5, W5h, W5l, 1024 * 512 / 4);
    w5max_mfma_kernel<<<dim3(16, 8, BATCH), 256, 0, stream>>>(CATh, CATl, W5h, W5l, b5, PART);
    greduce_kernel<<<8, 256, 0, stream>>>(PART, G);
    fc_kernel<<<4096, 256, 0, stream>>>(G, Wfc, bfc, D0);

    upconv_kernel<<<(2 * 32 * 32 * 32 + 255) / 256, 256, 0, stream>>>(D0, Wd1, bd1, DEC1,
                                                                      64, 32, 16, 16,
                                                                      2 * 32 * 32 * 32, 1);
    upconv_kernel<<<(2 * 16 * 64 * 64 + 255) / 256, 256, 0, stream>>>(DEC1, Wd2, bd2, DEC2,
                                                                      32, 16, 32, 32,
                                                                      2 * 16 * 64 * 64, 1);
    upconv_kernel<<<(2 * 1 * 128 * 128 + 255) / 256, 256, 0, stream>>>(DEC2, Wd3, bd3, out,
                                                                       16, 1, 64, 64,
                                                                       2 * 1 * 128 * 128, 0);
}

// Round 4
// 653.155 us; speedup vs baseline: 3.1954x; 1.1285x over previous
//
#include <hip/hip_runtime.h>
#include <hip/hip_bf16.h>

#define N_PTS 2048
#define BATCH 2
#define KNN 40

typedef __attribute__((ext_vector_type(8))) short bf16x8;
typedef __attribute__((ext_vector_type(16))) float f32x16;

__device__ __forceinline__ float lrelu(float v, float s) {
    return v >= 0.f ? v : s * v;
}

// ---------------- prefix: conv (5,3)/(5,1) + lrelu(0.01) -> H (B,N,2) ----------------
__global__ void prefix_kernel(const float* __restrict__ x, const float* __restrict__ Wc,
                              const float* __restrict__ bc, float* __restrict__ H) {
    int t = blockIdx.x * 256 + threadIdx.x;
    if (t >= BATCH * N_PTS) return;
    int b = t >> 11, n = t & 2047;
    #pragma unroll
    for (int oh = 0; oh < 2; ++oh) {
        float acc = bc[0];
        #pragma unroll
        for (int kh = 0; kh < 5; ++kh) {
            const float* xr = x + ((size_t)b * 10 + oh * 5 + kh) * N_PTS;
            #pragma unroll
            for (int kw = 0; kw < 3; ++kw) {
                int nn = n + kw - 1;
                if (nn >= 0 && nn < N_PTS) acc += xr[nn] * Wc[kh * 3 + kw];
            }
        }
        H[(size_t)t * 2 + oh] = lrelu(acc, 0.01f);
    }
}

// ---------------- xx[b,n] = sum_c X[b,n,c]^2 ----------------
__global__ void xx_kernel(const float* __restrict__ X, int S, long bsX, int C,
                          float* __restrict__ XX) {
    int t = blockIdx.x * 256 + threadIdx.x;
    if (t >= BATCH * N_PTS) return;
    int b = t >> 11, n = t & 2047;
    const float* row = X + (size_t)b * bsX + (size_t)n * S;
    float s = 0.f;
    for (int c = 0; c < C; ++c) { float v = row[c]; s += v * v; }
    XX[t] = s;
}

// ---------------- gram small (C=2, stage 1): 64x64 tile, 4x4/thread ----------------
__global__ __launch_bounds__(256) void gram_small_kernel(const float* __restrict__ X,
                                                         const float* __restrict__ xx,
                                                         float* __restrict__ negd) {
    __shared__ float AsT[2][68];
    __shared__ float BsT[2][68];
    int tid = threadIdx.x;
    int r0 = blockIdx.y * 64, c0 = blockIdx.x * 64;
    int ty = tid >> 4, tx = tid & 15;
    float acc[4][4] = {};
    if (tid < 128) {
        int r = tid >> 1, c = tid & 1;
        AsT[c][r] = X[(size_t)(r0 + r) * 2 + c];
        BsT[c][r] = X[(size_t)(c0 + r) * 2 + c];
    }
    __syncthreads();
    #pragma unroll
    for (int k = 0; k < 2; ++k) {
        float4 a = *(const float4*)&AsT[k][ty * 4];
        float4 b = *(const float4*)&BsT[k][tx * 4];
        #pragma unroll
        for (int i = 0; i < 4; ++i)
            #pragma unroll
            for (int j = 0; j < 4; ++j)
                acc[i][j] += (&a.x)[i] * (&b.x)[j];
    }
    #pragma unroll
    for (int i = 0; i < 4; ++i) {
        int r = r0 + ty * 4 + i;
        float xr = xx[r];
        #pragma unroll
        for (int j = 0; j < 4; ++j) {
            int c = c0 + tx * 4 + j;
            negd[(size_t)r * N_PTS + c] = 2.0f * acc[i][j] - xr - xx[c];
        }
    }
}

// ---------------- gram big (C=64/128): 128x128 tile, 8x8/thread, split-col map ----------
template<int C, int STAGE>
__global__ __launch_bounds__(256) void gram_kernel(const float* __restrict__ X, int S,
                                                   const float* __restrict__ xx,
                                                   float* __restrict__ negd) {
    __shared__ float AsT[32][132];
    __shared__ float BsT[32][132];
    int tid = threadIdx.x;
    int r0 = blockIdx.y * 128, c0 = blockIdx.x * 128;
    int ty = tid >> 4, tx = tid & 15;
    float acc[8][8] = {};
    for (int k0 = 0; k0 < C; k0 += 32) {
        __syncthreads();
        #pragma unroll
        for (int p = 0; p < 16; ++p) {
            int i = tid + p * 256;
            int c = i & 31, rw = i >> 5;
            AsT[c][rw] = X[(size_t)(r0 + rw) * S + k0 + c];
            BsT[c][rw] = X[(size_t)(c0 + rw) * S + k0 + c];
        }
        __syncthreads();
        #pragma unroll 8
        for (int k = 0; k < 32; ++k) {
            float4 a0 = *(const float4*)&AsT[k][ty * 4];
            float4 a1 = *(const float4*)&AsT[k][64 + ty * 4];
            float4 b0 = *(const float4*)&BsT[k][tx * 4];
            float4 b1 = *(const float4*)&BsT[k][64 + tx * 4];
            #pragma unroll
            for (int i = 0; i < 4; ++i) {
                float av0 = (&a0.x)[i], av1 = (&a1.x)[i];
                #pragma unroll
                for (int j = 0; j < 4; ++j) {
                    float bv0 = (&b0.x)[j], bv1 = (&b1.x)[j];
                    acc[i][j]         += av0 * bv0;
                    acc[i][j + 4]     += av0 * bv1;
                    acc[i + 4][j]     += av1 * bv0;
                    acc[i + 4][j + 4] += av1 * bv1;
                }
            }
        }
    }
    float xc0[4], xc1[4];
    #pragma unroll
    for (int j = 0; j < 4; ++j) {
        xc0[j] = xx[c0 + tx * 4 + j];
        xc1[j] = xx[c0 + 64 + tx * 4 + j];
    }
    #pragma unroll
    for (int i = 0; i < 8; ++i) {
        int r = r0 + (i < 4 ? ty * 4 + i : 64 + ty * 4 + (i - 4));
        float xr = xx[r];
        float4 o0v, o1v;
        #pragma unroll
        for (int j = 0; j < 4; ++j) {
            (&o0v.x)[j] = 2.0f * acc[i][j] - xr - xc0[j];
            (&o1v.x)[j] = 2.0f * acc[i][j + 4] - xr - xc1[j];
        }
        *(float4*)&negd[(size_t)r * N_PTS + c0 + tx * 4] = o0v;
        *(float4*)&negd[(size_t)r * N_PTS + c0 + 64 + tx * 4] = o1v;
    }
}

// ---------------- top-40 per row: 3-round radix select, wave-scan version ----------------
template<int STAGE>
__global__ __launch_bounds__(256) void topk_kernel(const float* __restrict__ negd,
                                                   int* __restrict__ idx_out) {
    __shared__ unsigned keys[N_PTS];
    __shared__ unsigned hist[4096];
    __shared__ unsigned wsum[4];
    __shared__ unsigned sc[4];
    int n = blockIdx.x;
    int tid = threadIdx.x;
    int wave = tid >> 6, lane = tid & 63;
    const float* row = negd + (size_t)n * N_PTS;
    for (int i = tid; i < 4096; i += 256) hist[i] = 0u;
    __syncthreads();
    for (int j = tid; j < N_PTS; j += 256) {
        unsigned u = __float_as_uint(row[j]);
        u = (u & 0x80000000u) ? ~u : (u | 0x80000000u);
        keys[j] = u;
        atomicAdd(&hist[u >> 20], 1u);
    }
    __syncthreads();
    unsigned r = KNN;
    // ---- round 1: bits [31:20] ----
    {
        unsigned chunk = 0;
        #pragma unroll
        for (int q = 0; q < 16; ++q) chunk += hist[tid * 16 + q];
        unsigned s = chunk;
        #pragma unroll
        for (int off = 1; off < 64; off <<= 1) {
            unsigned v = __shfl_down(s, off);
            if (lane + off < 64) s += v;
        }
        if (lane == 0) wsum[wave] = s;
        __syncthreads();
        unsigned add = 0;
        for (int w = wave + 1; w < 4; ++w) add += wsum[w];
        unsigned St = s + add, Sn = St - chunk;
        if (St >= r && Sn < r) { sc[0] = (unsigned)tid; sc[1] = r - Sn; }
        __syncthreads();
        if (tid == 0) {
            int c = (int)sc[0]; unsigned rc = sc[1];
            unsigned cum = 0; int b = c * 16 + 15;
            for (;; --b) { cum += hist[b]; if (cum >= rc) break; }
            sc[0] = (unsigned)b; sc[1] = rc - (cum - hist[b]);
        }
        __syncthreads();
    }
    unsigned p1 = sc[0]; r = sc[1];
    __syncthreads();
    // ---- round 2: bits [19:8] among prefix==p1 ----
    for (int i = tid; i < 4096; i += 256) hist[i] = 0u;
    __syncthreads();
    for (int j = tid; j < N_PTS; j += 256)
        if ((keys[j] >> 20) == p1) atomicAdd(&hist[(keys[j] >> 8) & 0xFFFu], 1u);
    __syncthreads();
    {
        unsigned chunk = 0;
        #pragma unroll
        for (int q = 0; q < 16; ++q) chunk += hist[tid * 16 + q];
        unsigned s = chunk;
        #pragma unroll
        for (int off = 1; off < 64; off <<= 1) {
            unsigned v = __shfl_down(s, off);
            if (lane + off < 64) s += v;
        }
        if (lane == 0) wsum[wave] = s;
        __syncthreads();
        unsigned add = 0;
        for (int w = wave + 1; w < 4; ++w) add += wsum[w];
        unsigned St = s + add, Sn = St - chunk;
        if (St >= r && Sn < r) { sc[0] = (unsigned)tid; sc[1] = r - Sn; }
        __syncthreads();
        if (tid == 0) {
            int c = (int)sc[0]; unsigned rc = sc[1];
            unsigned cum = 0; int b = c * 16 + 15;
            for (;; --b) { cum += hist[b]; if (cum >= rc) break; }
            sc[0] = (unsigned)b; sc[1] = rc - (cum - hist[b]);
        }
        __syncthreads();
    }
    unsigned p2 = (p1 << 12) | sc[0]; r = sc[1];
    __syncthreads();
    // ---- round 3: bits [7:0] among prefix==p2 (1 bin/thread) ----
    hist[tid] = 0u;
    __syncthreads();
    for (int j = tid; j < N_PTS; j += 256)
        if ((keys[j] >> 8) == p2) atomicAdd(&hist[keys[j] & 0xFFu], 1u);
    __syncthreads();
    {
        unsigned chunk = hist[tid];
        unsigned s = chunk;
        #pragma unroll
        for (int off = 1; off < 64; off <<= 1) {
            unsigned v = __shfl_down(s, off);
            if (lane + off < 64) s += v;
        }
        if (lane == 0) wsum[wave] = s;
        __syncthreads();
        unsigned add = 0;
        for (int w = wave + 1; w < 4; ++w) add += wsum[w];
        unsigned St = s + add, Sn = St - chunk;
        if (St >= r && Sn < r) { sc[0] = (unsigned)tid; sc[1] = r - Sn; }
        __syncthreads();
    }
    unsigned T = (p2 << 8) | sc[0];
    unsigned r3 = sc[1];
    // ---- collect strictly-greater ----
    if (tid == 0) sc[2] = 0u;
    __syncthreads();
    int* out = idx_out + (size_t)n * KNN;
    for (int j = tid; j < N_PTS; j += 256)
        if (keys[j] > T) out[atomicAdd(&sc[2], 1u)] = j;
    __syncthreads();
    // ---- ties at T: take r3 lowest indices (matches lax.top_k stability) ----
    int last = -1;
    for (unsigned t = 0; t < r3; ++t) {
        unsigned m = 0xFFFFFFFFu;
        for (int j = tid; j < N_PTS; j += 256)
            if (keys[j] == T && j > last) { m = (unsigned)j; break; }
        hist[tid] = m;
        __syncthreads();
        for (int st = 128; st >= 1; st >>= 1) {
            if (tid < st) hist[tid] = min(hist[tid], hist[tid + st]);
            __syncthreads();
        }
        if (tid == 0) { out[KNN - (int)r3 + (int)t] = (int)hist[0]; sc[3] = hist[0]; }
        __syncthreads();
        last = (int)sc[3];
    }
}

// ---------------- YaT = X @ Wa^T ; ZT = X @ Wb^T - YaT + bias  (layout (B,N,O)) ---------
template<int C, int O, int STAGE>
__global__ __launch_bounds__(256) void ya_z_kernel(const float* __restrict__ X, int S, long bsX,
                                                   const float* __restrict__ W,
                                                   const float* __restrict__ bias,
                                                   float* __restrict__ YaT, float* __restrict__ ZT) {
    constexpr int KC = (C < 32) ? C : 32;
    __shared__ float XsT[KC][68];
    __shared__ float WaT[KC][68];
    __shared__ float WbT[KC][68];
    int b = blockIdx.z;
    const float* Xb = X + (size_t)b * bsX;
    int n0 = blockIdx.x * 64, o0 = blockIdx.y * 64;
    int tid = threadIdx.x, ty = tid >> 4, tx = tid & 15;
    float aa[4][4] = {}, ab[4][4] = {};
    for (int k0 = 0; k0 < C; k0 += KC) {
        __syncthreads();
        for (int i = tid; i < 64 * KC; i += 256) {
            int r = i / KC, c = i % KC;
            XsT[c][r] = Xb[(size_t)(n0 + r) * S + k0 + c];
            WaT[c][r] = W[(size_t)(o0 + r) * 2 * C + k0 + c];
            WbT[c][r] = W[(size_t)(o0 + r) * 2 * C + C + k0 + c];
        }
        __syncthreads();
        #pragma unroll
        for (int k = 0; k < KC; ++k) {
            float4 xv = *(const float4*)&XsT[k][ty * 4];
            float4 wa = *(const float4*)&WaT[k][tx * 4];
            float4 wb = *(const float4*)&WbT[k][tx * 4];
            #pragma unroll
            for (int i = 0; i < 4; ++i)
                #pragma unroll
                for (int j = 0; j < 4; ++j) {
                    aa[i][j] += (&xv.x)[i] * (&wa.x)[j];
                    ab[i][j] += (&xv.x)[i] * (&wb.x)[j];
                }
        }
    }
    #pragma unroll
    for (int i = 0; i < 4; ++i) {
        int n = n0 + ty * 4 + i;
        #pragma unroll
        for (int j = 0; j < 4; ++j) {
            int o = o0 + tx * 4 + j;
            size_t off = ((size_t)b * N_PTS + n) * O + o;
            YaT[off] = aa[i][j];
            ZT[off] = ab[i][j] - aa[i][j] + bias[o];
        }
    }
}

// ---------------- out[n,o] = max_k lrelu(YaT[idx[n,k],o] + ZT[n,o], 0.2) ----------------
template<int O, int STAGE>
__global__ __launch_bounds__(256) void edge_reduce_kernel(const float* __restrict__ YaT,
                                                          const float* __restrict__ ZT,
                                                          const int* __restrict__ IDX,
                                                          float* __restrict__ CATp, int coloff) {
    int b = blockIdx.y;
    int tid = threadIdx.x;
    int n = blockIdx.x * (256 / O) + tid / O;
    int o = tid & (O - 1);
    const float* Ya_b = YaT + (size_t)b * N_PTS * O;
    float z = ZT[((size_t)b * N_PTS + n) * O + o];
    const int* ir = IDX + ((size_t)b * N_PTS + n) * KNN;
    float acc = -3.4e38f;
    #pragma unroll 8
    for (int k = 0; k < KNN; ++k) {
        int m = ir[k];
        float v = Ya_b[(size_t)m * O + o] + z;
        acc = fmaxf(acc, lrelu(v, 0.2f));
    }
    CATp[((size_t)b * N_PTS + n) * 512 + coloff + o] = acc;
}

// ---------------- fp32 -> bf16 hi/lo split ----------------
__global__ void cvt_split_kernel(const float* __restrict__ src, short* __restrict__ hi,
                                 short* __restrict__ lo, int total4) {
    int t = blockIdx.x * 256 + threadIdx.x;
    if (t >= total4) return;
    float4 v = ((const float4*)src)[t];
    short4 h, l;
    #pragma unroll
    for (int j = 0; j < 4; ++j) {
        float x = (&v.x)[j];
        __hip_bfloat16 hb = __float2bfloat16(x);
        float hf = __bfloat162float(hb);
        __hip_bfloat16 lb = __float2bfloat16(x - hf);
        (&h.x)[j] = *reinterpret_cast<short*>(&hb);
        (&l.x)[j] = *reinterpret_cast<short*>(&lb);
    }
    ((short4*)hi)[t] = h;
    ((short4*)lo)[t] = l;
}

// ---------------- w5max: split-bf16 3-pass MFMA, L2-direct, no LDS staging --------------
__global__ __launch_bounds__(256) void w5max_mfma_kernel(
        const short* __restrict__ Ah, const short* __restrict__ Al,
        const short* __restrict__ Bh, const short* __restrict__ Bl,
        const float* __restrict__ b5, float* __restrict__ PART) {
    __shared__ float red[2][128];
    int b = blockIdx.z;
    int tid = threadIdx.x;
    int wave = tid >> 6, lane = tid & 63;
    int wm = wave >> 1, wn = wave & 1;
    int m0 = blockIdx.x * 128 + wm * 64;
    int o0 = blockIdx.y * 128 + wn * 64;
    int rr = lane & 31;
    int kg = lane >> 5;
    const int FS = 32 * 512;
    const short* pAh = Ah + ((size_t)b * N_PTS + m0 + rr) * 512 + kg * 8;
    const short* pAl = Al + ((size_t)b * N_PTS + m0 + rr) * 512 + kg * 8;
    const short* pBh = Bh + (size_t)(o0 + rr) * 512 + kg * 8;
    const short* pBl = Bl + (size_t)(o0 + rr) * 512 + kg * 8;
    f32x16 a00 = {}, a01 = {}, a10 = {}, a11 = {};
    bf16x8 ah0 = *(const bf16x8*)(pAh);
    bf16x8 ah1 = *(const bf16x8*)(pAh + FS);
    bf16x8 al0 = *(const bf16x8*)(pAl);
    bf16x8 al1 = *(const bf16x8*)(pAl + FS);
    bf16x8 bh0 = *(const bf16x8*)(pBh);
    bf16x8 bh1 = *(const bf16x8*)(pBh + FS);
    bf16x8 bl0 = *(const bf16x8*)(pBl);
    bf16x8 bl1 = *(const bf16x8*)(pBl + FS);
    #pragma unroll 2
    for (int kc = 0; kc < 32; ++kc) {
        int kn = ((kc + 1) & 31) * 16;
        bf16x8 nah0 = *(const bf16x8*)(pAh + kn);
        bf16x8 nah1 = *(const bf16x8*)(pAh + kn + FS);
        bf16x8 nal0 = *(const bf16x8*)(pAl + kn);
        bf16x8 nal1 = *(const bf16x8*)(pAl + kn + FS);
        bf16x8 nbh0 = *(const bf16x8*)(pBh + kn);
        bf16x8 nbh1 = *(const bf16x8*)(pBh + kn + FS);
        bf16x8 nbl0 = *(const bf16x8*)(pBl + kn);
        bf16x8 nbl1 = *(const bf16x8*)(pBl + kn + FS);
        a00 = __builtin_amdgcn_mfma_f32_32x32x16_bf16(ah0, bh0, a00, 0, 0, 0);
        a00 = __builtin_amdgcn_mfma_f32_32x32x16_bf16(ah0, bl0, a00, 0, 0, 0);
        a00 = __builtin_amdgcn_mfma_f32_32x32x16_bf16(al0, bh0, a00, 0, 0, 0);
        a01 = __builtin_amdgcn_mfma_f32_32x32x16_bf16(ah0, bh1, a01, 0, 0, 0);
        a01 = __builtin_amdgcn_mfma_f32_32x32x16_bf16(ah0, bl1, a01, 0, 0, 0);
        a01 = __builtin_amdgcn_mfma_f32_32x32x16_bf16(al0, bh1, a01, 0, 0, 0);
        a10 = __builtin_amdgcn_mfma_f32_32x32x16_bf16(ah1, bh0, a10, 0, 0, 0);
        a10 = __builtin_amdgcn_mfma_f32_32x32x16_bf16(ah1, bl0, a10, 0, 0, 0);
        a10 = __builtin_amdgcn_mfma_f32_32x32x16_bf16(al1, bh0, a10, 0, 0, 0);
        a11 = __builtin_amdgcn_mfma_f32_32x32x16_bf16(ah1, bh1, a11, 0, 0, 0);
        a11 = __builtin_amdgcn_mfma_f32_32x32x16_bf16(ah1, bl1, a11, 0, 0, 0);
        a11 = __builtin_amdgcn_mfma_f32_32x32x16_bf16(al1, bh1, a11, 0, 0, 0);
        ah0 = nah0; ah1 = nah1; al0 = nal0; al1 = nal1;
        bh0 = nbh0; bh1 = nbh1; bl0 = nbl0; bl1 = nbl1;
    }
    #pragma unroll
    for (int fn = 0; fn < 2; ++fn) {
        float bo = b5[o0 + fn * 32 + rr];
        float m = -3.4e38f;
        #pragma unroll
        for (int r = 0; r < 16; ++r) {
            float v0 = (fn == 0) ? a00[r] : a01[r];
            float v1 = (fn == 0) ? a10[r] : a11[r];
            m = fmaxf(m, lrelu(v0 + bo, 0.2f));
            m = fmaxf(m, lrelu(v1 + bo, 0.2f));
        }
        m = fmaxf(m, __shfl_xor(m, 32));
        red[wm][wn * 64 + fn * 32 + rr] = m;
    }
    __syncthreads();
    if (tid < 128)
        PART[((size_t)b * 16 + blockIdx.x) * 1024 + blockIdx.y * 128 + tid] =
            fmaxf(red[0][tid], red[1][tid]);
}

__global__ void greduce_kernel(const float* __restrict__ PART, float* __restrict__ G) {
    int t = blockIdx.x * 256 + threadIdx.x;
    if (t >= BATCH * 1024) return;
    int b = t >> 10, o = t & 1023;
    const float* p = PART + (size_t)b * 16 * 1024 + o;
    float m = -3.4e38f;
    for (int nb = 0; nb < 16; ++nb) m = fmaxf(m, p[(size_t)nb * 1024]);
    G[t] = m;
}

// ---------------- FC: D0[b,j] = lrelu(g[b,:] . Wfc[j,:] + bfc[j]) ----------------
__global__ __launch_bounds__(256) void fc_kernel(const float* __restrict__ G,
                                                 const float* __restrict__ Wfc,
                                                 const float* __restrict__ bfc,
                                                 float* __restrict__ D0) {
    __shared__ float gl[2][1024];
    int tid = threadIdx.x;
    for (int i = tid; i < 2048; i += 256) gl[i >> 10][i & 1023] = G[i];
    __syncthreads();
    int wave = tid >> 6, lane = tid & 63;
    int j = blockIdx.x * 4 + wave;
    const float* wr = Wfc + (size_t)j * 1024;
    float a0 = 0.f, a1 = 0.f;
    for (int i = lane; i < 1024; i += 64) {
        float w = wr[i];
        a0 += w * gl[0][i];
        a1 += w * gl[1][i];
    }
    #pragma unroll
    for (int off = 32; off; off >>= 1) { a0 += __shfl_xor(a0, off); a1 += __shfl_xor(a1, off); }
    if (lane == 0) {
        float bb = bfc[j];
        D0[j] = lrelu(a0 + bb, 0.2f);
        D0[16384 + j] = lrelu(a1 + bb, 0.2f);
    }
}

// ---------------- fused up2 + conv3x3: quad kernel (2x2 outputs per thread) --------------
// one thread owns output quad (2p,2q),(2p,2q+1),(2p+1,2q),(2p+1,2q+1); reads 3x3 input
// neighborhood around (p,q) with hoisted masks/offsets; co = blockIdx.y (uniform -> s_load W)
template<int CI, int CO, int HI, int WI, int RELU>
__global__ __launch_bounds__(256) void upconv_quad_kernel(const float* __restrict__ in,
                                                          const float* __restrict__ W,
                                                          const float* __restrict__ bias,
                                                          float* __restrict__ out) {
    const int qid = blockIdx.x * 256 + threadIdx.x;
    const int p = qid / WI, q = qid % WI;
    const int co = blockIdx.y, b = blockIdx.z;
    const int HO = HI * 2, WO = WI * 2;

    // hoisted 3x3 offsets + masks (ci-independent)
    int off[3][3];
    float msk[3][3];
    #pragma unroll
    for (int r = 0; r < 3; ++r) {
        int pr = p - 1 + r;
        float rm = (pr >= 0 && pr < HI) ? 1.f : 0.f;
        int prc = min(max(pr, 0), HI - 1);
        #pragma unroll
        for (int c = 0; c < 3; ++c) {
            int qc = q - 1 + c;
            float cm = (qc >= 0 && qc < WI) ? 1.f : 0.f;
            int qcc = min(max(qc, 0), WI - 1);
            off[r][c] = prc * WI + qcc;
            msk[r][c] = rm * cm;
        }
    }
    const float* inb = in + (size_t)(b * CI) * HI * WI;
    const float* wco = W + (size_t)co * CI * 9;
    float bb = bias[co];
    float a00 = bb, a01 = bb, a10 = bb, a11 = bb;
    // row maps: even y uses in-rows {0,1,1}, odd y {1,1,2}; same for x
    const int me[3] = {0, 1, 1}, mo[3] = {1, 1, 2};
    #pragma unroll 4
    for (int ci = 0; ci < CI; ++ci) {
        const float* ip = inb + (size_t)ci * HI * WI;
        const float* wp = wco + ci * 9;
        float v[3][3];
        #pragma unroll
        for (int r = 0; r < 3; ++r)
            #pragma unroll
            for (int c = 0; c < 3; ++c)
                v[r][c] = msk[r][c] * ip[off[r][c]];
        #pragma unroll
        for (int dy = 0; dy < 3; ++dy) {
            #pragma unroll
            for (int dx = 0; dx < 3; ++dx) {
                float w = wp[dy * 3 + dx];
                a00 += w * v[me[dy]][me[dx]];
                a01 += w * v[me[dy]][mo[dx]];
                a10 += w * v[mo[dy]][me[dx]];
                a11 += w * v[mo[dy]][mo[dx]];
            }
        }
    }
    if (RELU) {
        a00 = lrelu(a00, 0.2f); a01 = lrelu(a01, 0.2f);
        a10 = lrelu(a10, 0.2f); a11 = lrelu(a11, 0.2f);
    }
    float* ob = out + ((size_t)(b * CO + co) * HO + 2 * p) * WO + 2 * q;
    float2 r0 = {a00, a01}, r1 = {a10, a11};
    *(float2*)ob = r0;
    *(float2*)(ob + WO) = r1;
}

extern "C" void kernel_launch(void* const* d_in, const int* in_sizes, int n_in,
                              void* d_out, int out_size, void* d_ws, size_t ws_size,
                              hipStream_t stream) {
    const float* x   = (const float*)d_in[0];
    const float* Wc  = (const float*)d_in[1];
    const float* bc  = (const float*)d_in[2];
    const float* W1  = (const float*)d_in[3];
    const float* b1  = (const float*)d_in[4];
    const float* W2  = (const float*)d_in[5];
    const float* b2  = (const float*)d_in[6];
    const float* W3  = (const float*)d_in[7];
    const float* b3  = (const float*)d_in[8];
    const float* W4  = (const float*)d_in[9];
    const float* b4  = (const float*)d_in[10];
    const float* W5  = (const float*)d_in[11];
    const float* b5  = (const float*)d_in[12];
    const float* Wfc = (const float*)d_in[13];
    const float* bfc = (const float*)d_in[14];
    const float* Wd1 = (const float*)d_in[15];
    const float* bd1 = (const float*)d_in[16];
    const float* Wd2 = (const float*)d_in[17];
    const float* bd2 = (const float*)d_in[18];
    const float* Wd3 = (const float*)d_in[19];
    const float* bd3 = (const float*)d_in[20];
    float* out = (float*)d_out;

    char* ws = (char*)d_ws;
    float* Hb   = (float*)(ws + 0);          // (B,N,2)
    float* CAT  = (float*)(ws + 32768);      // (B,N,512)    8 MB
    float* YaT  = (float*)(ws + 8421376);    // (B,N,256)    4 MB
    float* ZT   = (float*)(ws + 12615680);   // (B,N,256)    4 MB
    float* NEGD = (float*)(ws + 16809984);   // (N,N) 16 MB (reused per batch)
    short* CATh = (short*)(ws + 16809984);   // (B,N,512) bf16  4 MB (aliases NEGD after stages)
    short* CATl = (short*)(ws + 21004288);   // 4 MB
    short* W5h  = (short*)(ws + 25198592);   // (1024,512) bf16 1 MB
    short* W5l  = (short*)(ws + 26247168);   // 1 MB
    float* XX   = (float*)(ws + 33587200);   // (B,N)
    int*   IDX  = (int*)  (ws + 33603584);   // (B,N,40)
    float* PART = (float*)(ws + 34258944);   // (B,16,1024)
    float* G    = (float*)(ws + 34521088);   // (B,1024)
    float* D0   = (float*)(ws + 34529280);   // (B,16384)
    float* DEC1 = (float*)(ws + 34660352);   // (B,32,32,32)
    float* DEC2 = (float*)(ws + 34922496);   // (B,16,64,64)

    prefix_kernel<<<16, 256, 0, stream>>>(x, Wc, bc, Hb);

    // ---- stage 1: C=2, O=64 ----
    xx_kernel<<<16, 256, 0, stream>>>(Hb, 2, (long)N_PTS * 2, 2, XX);
    for (int b = 0; b < BATCH; ++b) {
        gram_small_kernel<<<dim3(32, 32), 256, 0, stream>>>(Hb + (size_t)b * N_PTS * 2,
                                                            XX + b * N_PTS, NEGD);
        topk_kernel<1><<<N_PTS, 256, 0, stream>>>(NEGD, IDX + (size_t)b * N_PTS * KNN);
    }
    ya_z_kernel<2, 64, 1><<<dim3(32, 1, BATCH), 256, 0, stream>>>(Hb, 2, (long)N_PTS * 2,
                                                                  W1, b1, YaT, ZT);
    edge_reduce_kernel<64, 1><<<dim3(N_PTS * 64 / 256, BATCH), 256, 0, stream>>>(YaT, ZT, IDX,
                                                                                 CAT, 0);
    // ---- stage 2: C=64, O=64 ----
    xx_kernel<<<16, 256, 0, stream>>>(CAT + 0, 512, (long)N_PTS * 512, 64, XX);
    for (int b = 0; b < BATCH; ++b) {
        gram_kernel<64, 2><<<dim3(16, 16), 256, 0, stream>>>(CAT + 0 + (size_t)b * N_PTS * 512,
                                                             512, XX + b * N_PTS, NEGD);
        topk_kernel<2><<<N_PTS, 256, 0, stream>>>(NEGD, IDX + (size_t)b * N_PTS * KNN);
    }
    ya_z_kernel<64, 64, 2><<<dim3(32, 1, BATCH), 256, 0, stream>>>(CAT + 0, 512,
                                                                   (long)N_PTS * 512,
                                                                   W2, b2, YaT, ZT);
    edge_reduce_kernel<64, 2><<<dim3(N_PTS * 64 / 256, BATCH), 256, 0, stream>>>(YaT, ZT, IDX,
                                                                                 CAT, 64);
    // ---- stage 3: C=64, O=128 ----
    xx_kernel<<<16, 256, 0, stream>>>(CAT + 64, 512, (long)N_PTS * 512, 64, XX);
    for (int b = 0; b < BATCH; ++b) {
        gram_kernel<64, 3><<<dim3(16, 16), 256, 0, stream>>>(CAT + 64 + (size_t)b * N_PTS * 512,
                                                             512, XX + b * N_PTS, NEGD);
        topk_kernel<3><<<N_PTS, 256, 0, stream>>>(NEGD, IDX + (size_t)b * N_PTS * KNN);
    }
    ya_z_kernel<64, 128, 3><<<dim3(32, 2, BATCH), 256, 0, stream>>>(CAT + 64, 512,
                                                                    (long)N_PTS * 512,
                                                                    W3, b3, YaT, ZT);
    edge_reduce_kernel<128, 3><<<dim3(N_PTS * 128 / 256, BATCH), 256, 0, stream>>>(YaT, ZT, IDX,
                                                                                   CAT, 128);
    // ---- stage 4: C=128, O=256 ----
    xx_kernel<<<16, 256, 0, stream>>>(CAT + 128, 512, (long)N_PTS * 512, 128, XX);
    for (int b = 0; b < BATCH; ++b) {
        gram_kernel<128, 4><<<dim3(16, 16), 256, 0, stream>>>(CAT + 128 + (size_t)b * N_PTS * 512,
                                                              512, XX + b * N_PTS, NEGD);
        topk_kernel<4><<<N_PTS, 256, 0, stream>>>(NEGD, IDX + (size_t)b * N_PTS * KNN);
    }
    ya_z_kernel<128, 256, 4><<<dim3(32, 4, BATCH), 256, 0, stream>>>(CAT + 128, 512,
                                                                     (long)N_PTS * 512,
                                                                     W4, b4, YaT, ZT);
    edge_reduce_kernel<256, 4><<<dim3(N_PTS * 256 / 256, BATCH), 256, 0, stream>>>(YaT, ZT, IDX,
                                                                                   CAT, 256);

    // ---- global feature: split-bf16 MFMA W5 + max ----
    cvt_split_kernel<<<(BATCH * N_PTS * 512 / 4 + 255) / 256, 256, 0, stream>>>(
        CAT, CATh, CATl, BATCH * N_PTS * 512 / 4);
    cvt_split_kernel<<<(1024 * 512 / 4 + 255) / 256, 256, 0, stream>>>(
        W5, W5h, W5l, 1024 * 512 / 4);
    w5max_mfma_kernel<<<dim3(16, 8, BATCH), 256, 0, stream>>>(CATh, CATl, W5h, W5l, b5, PART);
    greduce_kernel<<<8, 256, 0, stream>>>(PART, G);
    fc_kernel<<<4096, 256, 0, stream>>>(G, Wfc, bfc, D0);

    // ---- decoder: quad upconvs ----
    upconv_quad_kernel<64, 32, 16, 16, 1><<<dim3(1, 32, BATCH), 256, 0, stream>>>(D0, Wd1, bd1,
                                                                                  DEC1);
    upconv_quad_kernel<32, 16, 32, 32, 1><<<dim3(4, 16, BATCH), 256, 0, stream>>>(DEC1, Wd2, bd2,
                                                                                  DEC2);
    upconv_quad_kernel<16, 1, 64, 64, 0><<<dim3(16, 1, BATCH), 256, 0, stream>>>(DEC2, Wd3, bd3,
                                                                                 out);
}

// Round 5
// 527.095 us; speedup vs baseline: 3.9597x; 1.2392x over previous
//
#include <hip/hip_runtime.h>
#include <hip/hip_bf16.h>

#define N_PTS 2048
#define BATCH 2
#define KNN 40

typedef __attribute__((ext_vector_type(8))) short bf16x8;
typedef __attribute__((ext_vector_type(16))) float f32x16;

__device__ __forceinline__ float lrelu(float v, float s) {
    return v >= 0.f ? v : s * v;
}

// ---------------- prefix: conv (5,3)/(5,1) + lrelu(0.01) -> H (B,N,2) ----------------
__global__ void prefix_kernel(const float* __restrict__ x, const float* __restrict__ Wc,
                              const float* __restrict__ bc, float* __restrict__ H) {
    int t = blockIdx.x * 256 + threadIdx.x;
    if (t >= BATCH * N_PTS) return;
    int b = t >> 11, n = t & 2047;
    #pragma unroll
    for (int oh = 0; oh < 2; ++oh) {
        float acc = bc[0];
        #pragma unroll
        for (int kh = 0; kh < 5; ++kh) {
            const float* xr = x + ((size_t)b * 10 + oh * 5 + kh) * N_PTS;
            #pragma unroll
            for (int kw = 0; kw < 3; ++kw) {
                int nn = n + kw - 1;
                if (nn >= 0 && nn < N_PTS) acc += xr[nn] * Wc[kh * 3 + kw];
            }
        }
        H[(size_t)t * 2 + oh] = lrelu(acc, 0.01f);
    }
}

// ---------------- xx[b,n] = sum_c X[b,n,c]^2 ----------------
__global__ void xx_kernel(const float* __restrict__ X, int S, long bsX, int C,
                          float* __restrict__ XX) {
    int t = blockIdx.x * 256 + threadIdx.x;
    if (t >= BATCH * N_PTS) return;
    int b = t >> 11, n = t & 2047;
    const float* row = X + (size_t)b * bsX + (size_t)n * S;
    float s = 0.f;
    for (int c = 0; c < C; ++c) { float v = row[c]; s += v * v; }
    XX[t] = s;
}

// ---------------- gram small (C=2, stage 1): 64x64 tile, 4x4/thread, z-batch -----------
__global__ __launch_bounds__(256) void gram_small_kernel(const float* __restrict__ X, long bsX,
                                                         long nstride,
                                                         const float* __restrict__ xx,
                                                         float* __restrict__ negd) {
    __shared__ float AsT[2][68];
    __shared__ float BsT[2][68];
    int bz = blockIdx.z;
    const float* Xb = X + (size_t)bz * bsX;
    const float* xxb = xx + (size_t)bz * N_PTS;
    float* nd = negd + (size_t)bz * nstride;
    int tid = threadIdx.x;
    int r0 = blockIdx.y * 64, c0 = blockIdx.x * 64;
    int ty = tid >> 4, tx = tid & 15;
    float acc[4][4] = {};
    if (tid < 128) {
        int r = tid >> 1, c = tid & 1;
        AsT[c][r] = Xb[(size_t)(r0 + r) * 2 + c];
        BsT[c][r] = Xb[(size_t)(c0 + r) * 2 + c];
    }
    __syncthreads();
    #pragma unroll
    for (int k = 0; k < 2; ++k) {
        float4 a = *(const float4*)&AsT[k][ty * 4];
        float4 b = *(const float4*)&BsT[k][tx * 4];
        #pragma unroll
        for (int i = 0; i < 4; ++i)
            #pragma unroll
            for (int j = 0; j < 4; ++j)
                acc[i][j] += (&a.x)[i] * (&b.x)[j];
    }
    #pragma unroll
    for (int i = 0; i < 4; ++i) {
        int r = r0 + ty * 4 + i;
        float xr = xxb[r];
        #pragma unroll
        for (int j = 0; j < 4; ++j) {
            int c = c0 + tx * 4 + j;
            nd[(size_t)r * N_PTS + c] = 2.0f * acc[i][j] - xr - xxb[c];
        }
    }
}

// ---------------- gram big (C=64/128): 128x128 tile, 512 thr, 4x8/thread ----------------
// split-col map (tx*4 and 64+tx*4): B-reads 2-way (free), staging pad 133 conflict-free
template<int C, int STAGE>
__global__ __launch_bounds__(512) void gram_kernel(const float* __restrict__ X, int S, long bsX,
                                                   long nstride,
                                                   const float* __restrict__ xx,
                                                   float* __restrict__ negd) {
    __shared__ float AsT[32][133];
    __shared__ float BsT[32][133];
    int bz = blockIdx.z;
    const float* Xb = X + (size_t)bz * bsX;
    const float* xxb = xx + (size_t)bz * N_PTS;
    float* nd = negd + (size_t)bz * nstride;
    int tid = threadIdx.x;
    int r0 = blockIdx.y * 128, c0 = blockIdx.x * 128;
    int ty = tid >> 4, tx = tid & 15;   // ty 0..31, tx 0..15
    float acc[4][8] = {};
    for (int k0 = 0; k0 < C; k0 += 32) {
        __syncthreads();
        #pragma unroll
        for (int p = 0; p < 8; ++p) {
            int i = tid + p * 512;
            int c = i & 31, rw = i >> 5;
            AsT[c][rw] = Xb[(size_t)(r0 + rw) * S + k0 + c];
            BsT[c][rw] = Xb[(size_t)(c0 + rw) * S + k0 + c];
        }
        __syncthreads();
        #pragma unroll 4
        for (int k = 0; k < 32; ++k) {
            float4 a  = *(const float4*)&AsT[k][ty * 4];
            float4 b0 = *(const float4*)&BsT[k][tx * 4];
            float4 b1 = *(const float4*)&BsT[k][64 + tx * 4];
            #pragma unroll
            for (int i = 0; i < 4; ++i) {
                float av = (&a.x)[i];
                #pragma unroll
                for (int j = 0; j < 4; ++j) {
                    acc[i][j]     += av * (&b0.x)[j];
                    acc[i][j + 4] += av * (&b1.x)[j];
                }
            }
        }
    }
    float xc0[4], xc1[4];
    #pragma unroll
    for (int j = 0; j < 4; ++j) {
        xc0[j] = xxb[c0 + tx * 4 + j];
        xc1[j] = xxb[c0 + 64 + tx * 4 + j];
    }
    #pragma unroll
    for (int i = 0; i < 4; ++i) {
        int r = r0 + ty * 4 + i;
        float xr = xxb[r];
        float4 o0v, o1v;
        #pragma unroll
        for (int j = 0; j < 4; ++j) {
            (&o0v.x)[j] = 2.0f * acc[i][j] - xr - xc0[j];
            (&o1v.x)[j] = 2.0f * acc[i][j + 4] - xr - xc1[j];
        }
        *(float4*)&nd[(size_t)r * N_PTS + c0 + tx * 4] = o0v;
        *(float4*)&nd[(size_t)r * N_PTS + c0 + 64 + tx * 4] = o1v;
    }
}

// ---------------- top-40 per row: radix select with candidate compaction ----------------
// exact, index-ascending ties (matches stable lax.top_k; output order irrelevant for max)
template<int STAGE>
__global__ __launch_bounds__(256) void topk_kernel(const float* __restrict__ negd, long nstride,
                                                   int* __restrict__ idx_out) {
    __shared__ unsigned keys[N_PTS];
    __shared__ unsigned hist[4096];
    __shared__ unsigned short cand[N_PTS];
    __shared__ unsigned wsum[4];
    __shared__ unsigned sc[4];
    int bz = blockIdx.y;
    int n = blockIdx.x;
    int tid = threadIdx.x;
    int wave = tid >> 6, lane = tid & 63;
    const float* row = negd + (size_t)bz * nstride + (size_t)n * N_PTS;
    // ---- pass 1: load + round-1 histogram (bits 31:20) ----
    for (int i = tid; i < 4096; i += 256) hist[i] = 0u;
    __syncthreads();
    for (int j = tid; j < N_PTS; j += 256) {
        unsigned u = __float_as_uint(row[j]);
        u = (u & 0x80000000u) ? ~u : (u | 0x80000000u);
        keys[j] = u;
        atomicAdd(&hist[u >> 20], 1u);
    }
    __syncthreads();
    unsigned r = KNN;
    // ---- round 1 scan ----
    {
        unsigned chunk = 0;
        #pragma unroll
        for (int q = 0; q < 16; ++q) chunk += hist[tid * 16 + q];
        unsigned s = chunk;
        #pragma unroll
        for (int off = 1; off < 64; off <<= 1) {
            unsigned v = __shfl_down(s, off);
            if (lane + off < 64) s += v;
        }
        if (lane == 0) wsum[wave] = s;
        __syncthreads();
        unsigned add = 0;
        for (int w = wave + 1; w < 4; ++w) add += wsum[w];
        unsigned St = s + add, Sn = St - chunk;
        if (St >= r && Sn < r) { sc[0] = (unsigned)tid; sc[1] = r - Sn; }
        __syncthreads();
        if (tid == 0) {
            int c = (int)sc[0]; unsigned rc = sc[1];
            unsigned cum = 0; int b = c * 16 + 15;
            for (;; --b) { cum += hist[b]; if (cum >= rc) break; }
            sc[0] = (unsigned)b; sc[1] = rc - (cum - hist[b]);
        }
        __syncthreads();
    }
    unsigned p1 = sc[0]; r = sc[1];
    __syncthreads();
    // ---- compact candidates with prefix p1 ----
    if (tid == 0) sc[2] = 0u;
    __syncthreads();
    for (int j = tid; j < N_PTS; j += 256)
        if ((keys[j] >> 20) == p1) cand[atomicAdd(&sc[2], 1u)] = (unsigned short)j;
    __syncthreads();
    int cnt = (int)sc[2];
    // ---- round 2: bits [19:8] over candidates ----
    for (int i = tid; i < 4096; i += 256) hist[i] = 0u;
    __syncthreads();
    for (int i = tid; i < cnt; i += 256)
        atomicAdd(&hist[(keys[cand[i]] >> 8) & 0xFFFu], 1u);
    __syncthreads();
    {
        unsigned chunk = 0;
        #pragma unroll
        for (int q = 0; q < 16; ++q) chunk += hist[tid * 16 + q];
        unsigned s = chunk;
        #pragma unroll
        for (int off = 1; off < 64; off <<= 1) {
            unsigned v = __shfl_down(s, off);
            if (lane + off < 64) s += v;
        }
        if (lane == 0) wsum[wave] = s;
        __syncthreads();
        unsigned add = 0;
        for (int w = wave + 1; w < 4; ++w) add += wsum[w];
        unsigned St = s + add, Sn = St - chunk;
        if (St >= r && Sn < r) { sc[0] = (unsigned)tid; sc[1] = r - Sn; }
        __syncthreads();
        if (tid == 0) {
            int c = (int)sc[0]; unsigned rc = sc[1];
            unsigned cum = 0; int b = c * 16 + 15;
            for (;; --b) { cum += hist[b]; if (cum >= rc) break; }
            sc[0] = (unsigned)b; sc[1] = rc - (cum - hist[b]);
        }
        __syncthreads();
    }
    unsigned b2 = sc[0]; r = sc[1];
    __syncthreads();
    // ---- round 3: bits [7:0] over candidates with mid == b2 ----
    hist[tid] = 0u;
    __syncthreads();
    for (int i = tid; i < cnt; i += 256) {
        unsigned kk = keys[cand[i]];
        if (((kk >> 8) & 0xFFFu) == b2) atomicAdd(&hist[kk & 0xFFu], 1u);
    }
    __syncthreads();
    {
        unsigned chunk = hist[tid];
        unsigned s = chunk;
        #pragma unroll
        for (int off = 1; off < 64; off <<= 1) {
            unsigned v = __shfl_down(s, off);
            if (lane + off < 64) s += v;
        }
        if (lane == 0) wsum[wave] = s;
        __syncthreads();
        unsigned add = 0;
        for (int w = wave + 1; w < 4; ++w) add += wsum[w];
        unsigned St = s + add, Sn = St - chunk;
        if (St >= r && Sn < r) { sc[0] = (unsigned)tid; sc[1] = r - Sn; }
        __syncthreads();
    }
    unsigned T = (p1 << 20) | (b2 << 8) | sc[0];
    unsigned r3 = sc[1];
    // ---- collect strictly-greater (full pass; output order irrelevant) ----
    if (tid == 0) sc[2] = 0u;
    __syncthreads();
    int* out = idx_out + ((size_t)bz * N_PTS + n) * KNN;
    for (int j = tid; j < N_PTS; j += 256)
        if (keys[j] > T) out[atomicAdd(&sc[2], 1u)] = j;
    __syncthreads();
    // ---- ties at T: take r3 lowest indices from candidate list ----
    int last = -1;
    for (unsigned t = 0; t < r3; ++t) {
        unsigned m = 0xFFFFFFFFu;
        for (int i = tid; i < cnt; i += 256) {
            int j = cand[i];
            if (keys[j] == T && j > last && (unsigned)j < m) m = (unsigned)j;
        }
        hist[tid] = m;
        __syncthreads();
        for (int st = 128; st >= 1; st >>= 1) {
            if (tid < st) hist[tid] = min(hist[tid], hist[tid + st]);
            __syncthreads();
        }
        if (tid == 0) { out[KNN - (int)r3 + (int)t] = (int)hist[0]; sc[3] = hist[0]; }
        __syncthreads();
        last = (int)sc[3];
    }
}

// ---------------- YaT = X @ Wa^T ; ZT = X @ Wb^T - YaT + bias  (layout (B,N,O)) ---------
template<int C, int O, int STAGE>
__global__ __launch_bounds__(256) void ya_z_kernel(const float* __restrict__ X, int S, long bsX,
                                                   const float* __restrict__ W,
                                                   const float* __restrict__ bias,
                                                   float* __restrict__ YaT, float* __restrict__ ZT) {
    constexpr int KC = (C < 32) ? C : 32;
    __shared__ float XsT[KC][68];
    __shared__ float WaT[KC][68];
    __shared__ float WbT[KC][68];
    int b = blockIdx.z;
    const float* Xb = X + (size_t)b * bsX;
    int n0 = blockIdx.x * 64, o0 = blockIdx.y * 64;
    int tid = threadIdx.x, ty = tid >> 4, tx = tid & 15;
    float aa[4][4] = {}, ab[4][4] = {};
    for (int k0 = 0; k0 < C; k0 += KC) {
        __syncthreads();
        for (int i = tid; i < 64 * KC; i += 256) {
            int r = i / KC, c = i % KC;
            XsT[c][r] = Xb[(size_t)(n0 + r) * S + k0 + c];
            WaT[c][r] = W[(size_t)(o0 + r) * 2 * C + k0 + c];
            WbT[c][r] = W[(size_t)(o0 + r) * 2 * C + C + k0 + c];
        }
        __syncthreads();
        #pragma unroll
        for (int k = 0; k < KC; ++k) {
            float4 xv = *(const float4*)&XsT[k][ty * 4];
            float4 wa = *(const float4*)&WaT[k][tx * 4];
            float4 wb = *(const float4*)&WbT[k][tx * 4];
            #pragma unroll
            for (int i = 0; i < 4; ++i)
                #pragma unroll
                for (int j = 0; j < 4; ++j) {
                    aa[i][j] += (&xv.x)[i] * (&wa.x)[j];
                    ab[i][j] += (&xv.x)[i] * (&wb.x)[j];
                }
        }
    }
    #pragma unroll
    for (int i = 0; i < 4; ++i) {
        int n = n0 + ty * 4 + i;
        #pragma unroll
        for (int j = 0; j < 4; ++j) {
            int o = o0 + tx * 4 + j;
            size_t off = ((size_t)b * N_PTS + n) * O + o;
            YaT[off] = aa[i][j];
            ZT[off] = ab[i][j] - aa[i][j] + bias[o];
        }
    }
}

// ---------------- out[n,o] = max_k lrelu(YaT[idx[n,k],o] + ZT[n,o], 0.2) ----------------
template<int O, int STAGE>
__global__ __launch_bounds__(256) void edge_reduce_kernel(const float* __restrict__ YaT,
                                                          const float* __restrict__ ZT,
                                                          const int* __restrict__ IDX,
                                                          float* __restrict__ CATp, int coloff) {
    int b = blockIdx.y;
    int tid = threadIdx.x;
    int n = blockIdx.x * (256 / O) + tid / O;
    int o = tid & (O - 1);
    const float* Ya_b = YaT + (size_t)b * N_PTS * O;
    float z = ZT[((size_t)b * N_PTS + n) * O + o];
    const int* ir = IDX + ((size_t)b * N_PTS + n) * KNN;
    float acc = -3.4e38f;
    #pragma unroll 8
    for (int k = 0; k < KNN; ++k) {
        int m = ir[k];
        float v = Ya_b[(size_t)m * O + o] + z;
        acc = fmaxf(acc, lrelu(v, 0.2f));
    }
    CATp[((size_t)b * N_PTS + n) * 512 + coloff + o] = acc;
}

// ---------------- fp32 -> bf16 hi/lo split ----------------
__global__ void cvt_split_kernel(const float* __restrict__ src, short* __restrict__ hi,
                                 short* __restrict__ lo, int total4) {
    int t = blockIdx.x * 256 + threadIdx.x;
    if (t >= total4) return;
    float4 v = ((const float4*)src)[t];
    short4 h, l;
    #pragma unroll
    for (int j = 0; j < 4; ++j) {
        float x = (&v.x)[j];
        __hip_bfloat16 hb = __float2bfloat16(x);
        float hf = __bfloat162float(hb);
        __hip_bfloat16 lb = __float2bfloat16(x - hf);
        (&h.x)[j] = *reinterpret_cast<short*>(&hb);
        (&l.x)[j] = *reinterpret_cast<short*>(&lb);
    }
    ((short4*)hi)[t] = h;
    ((short4*)lo)[t] = l;
}

// ---------------- w5max: split-bf16 3-pass MFMA, L2-direct, no LDS staging --------------
__global__ __launch_bounds__(256) void w5max_mfma_kernel(
        const short* __restrict__ Ah, const short* __restrict__ Al,
        const short* __restrict__ Bh, const short* __restrict__ Bl,
        const float* __restrict__ b5, float* __restrict__ PART) {
    __shared__ float red[2][128];
    int b = blockIdx.z;
    int tid = threadIdx.x;
    int wave = tid >> 6, lane = tid & 63;
    int wm = wave >> 1, wn = wave & 1;
    int m0 = blockIdx.x * 128 + wm * 64;
    int o0 = blockIdx.y * 128 + wn * 64;
    int rr = lane & 31;
    int kg = lane >> 5;
    const int FS = 32 * 512;
    const short* pAh = Ah + ((size_t)b * N_PTS + m0 + rr) * 512 + kg * 8;
    const short* pAl = Al + ((size_t)b * N_PTS + m0 + rr) * 512 + kg * 8;
    const short* pBh = Bh + (size_t)(o0 + rr) * 512 + kg * 8;
    const short* pBl = Bl + (size_t)(o0 + rr) * 512 + kg * 8;
    f32x16 a00 = {}, a01 = {}, a10 = {}, a11 = {};
    bf16x8 ah0 = *(const bf16x8*)(pAh);
    bf16x8 ah1 = *(const bf16x8*)(pAh + FS);
    bf16x8 al0 = *(const bf16x8*)(pAl);
    bf16x8 al1 = *(const bf16x8*)(pAl + FS);
    bf16x8 bh0 = *(const bf16x8*)(pBh);
    bf16x8 bh1 = *(const bf16x8*)(pBh + FS);
    bf16x8 bl0 = *(const bf16x8*)(pBl);
    bf16x8 bl1 = *(const bf16x8*)(pBl + FS);
    #pragma unroll 2
    for (int kc = 0; kc < 32; ++kc) {
        int kn = ((kc + 1) & 31) * 16;
        bf16x8 nah0 = *(const bf16x8*)(pAh + kn);
        bf16x8 nah1 = *(const bf16x8*)(pAh + kn + FS);
        bf16x8 nal0 = *(const bf16x8*)(pAl + kn);
        bf16x8 nal1 = *(const bf16x8*)(pAl + kn + FS);
        bf16x8 nbh0 = *(const bf16x8*)(pBh + kn);
        bf16x8 nbh1 = *(const bf16x8*)(pBh + kn + FS);
        bf16x8 nbl0 = *(const bf16x8*)(pBl + kn);
        bf16x8 nbl1 = *(const bf16x8*)(pBl + kn + FS);
        a00 = __builtin_amdgcn_mfma_f32_32x32x16_bf16(ah0, bh0, a00, 0, 0, 0);
        a00 = __builtin_amdgcn_mfma_f32_32x32x16_bf16(ah0, bl0, a00, 0, 0, 0);
        a00 = __builtin_amdgcn_mfma_f32_32x32x16_bf16(al0, bh0, a00, 0, 0, 0);
        a01 = __builtin_amdgcn_mfma_f32_32x32x16_bf16(ah0, bh1, a01, 0, 0, 0);
        a01 = __builtin_amdgcn_mfma_f32_32x32x16_bf16(ah0, bl1, a01, 0, 0, 0);
        a01 = __builtin_amdgcn_mfma_f32_32x32x16_bf16(al0, bh1, a01, 0, 0, 0);
        a10 = __builtin_amdgcn_mfma_f32_32x32x16_bf16(ah1, bh0, a10, 0, 0, 0);
        a10 = __builtin_amdgcn_mfma_f32_32x32x16_bf16(ah1, bl0, a10, 0, 0, 0);
        a10 = __builtin_amdgcn_mfma_f32_32x32x16_bf16(al1, bh0, a10, 0, 0, 0);
        a11 = __builtin_amdgcn_mfma_f32_32x32x16_bf16(ah1, bh1, a11, 0, 0, 0);
        a11 = __builtin_amdgcn_mfma_f32_32x32x16_bf16(ah1, bl1, a11, 0, 0, 0);
        a11 = __builtin_amdgcn_mfma_f32_32x32x16_bf16(al1, bh1, a11, 0, 0, 0);
        ah0 = nah0; ah1 = nah1; al0 = nal0; al1 = nal1;
        bh0 = nbh0; bh1 = nbh1; bl0 = nbl0; bl1 = nbl1;
    }
    #pragma unroll
    for (int fn = 0; fn < 2; ++fn) {
        float bo = b5[o0 + fn * 32 + rr];
        float m = -3.4e38f;
        #pragma unroll
        for (int r = 0; r < 16; ++r) {
            float v0 = (fn == 0) ? a00[r] : a01[r];
            float v1 = (fn == 0) ? a10[r] : a11[r];
            m = fmaxf(m, lrelu(v0 + bo, 0.2f));
            m = fmaxf(m, lrelu(v1 + bo, 0.2f));
        }
        m = fmaxf(m, __shfl_xor(m, 32));
        red[wm][wn * 64 + fn * 32 + rr] = m;
    }
    __syncthreads();
    if (tid < 128)
        PART[((size_t)b * 16 + blockIdx.x) * 1024 + blockIdx.y * 128 + tid] =
            fmaxf(red[0][tid], red[1][tid]);
}

__global__ void greduce_kernel(const float* __restrict__ PART, float* __restrict__ G) {
    int t = blockIdx.x * 256 + threadIdx.x;
    if (t >= BATCH * 1024) return;
    int b = t >> 10, o = t & 1023;
    const float* p = PART + (size_t)b * 16 * 1024 + o;
    float m = -3.4e38f;
    for (int nb = 0; nb < 16; ++nb) m = fmaxf(m, p[(size_t)nb * 1024]);
    G[t] = m;
}

// ---------------- FC: D0[b,j] = lrelu(g[b,:] . Wfc[j,:] + bfc[j]) ----------------
__global__ __launch_bounds__(256) void fc_kernel(const float* __restrict__ G,
                                                 const float* __restrict__ Wfc,
                                                 const float* __restrict__ bfc,
                                                 float* __restrict__ D0) {
    __shared__ float gl[2][1024];
    int tid = threadIdx.x;
    for (int i = tid; i < 2048; i += 256) gl[i >> 10][i & 1023] = G[i];
    __syncthreads();
    int wave = tid >> 6, lane = tid & 63;
    int j = blockIdx.x * 4 + wave;
    const float* wr = Wfc + (size_t)j * 1024;
    float a0 = 0.f, a1 = 0.f;
    for (int i = lane; i < 1024; i += 64) {
        float w = wr[i];
        a0 += w * gl[0][i];
        a1 += w * gl[1][i];
    }
    #pragma unroll
    for (int off = 32; off; off >>= 1) { a0 += __shfl_xor(a0, off); a1 += __shfl_xor(a1, off); }
    if (lane == 0) {
        float bb = bfc[j];
        D0[j] = lrelu(a0 + bb, 0.2f);
        D0[16384 + j] = lrelu(a1 + bb, 0.2f);
    }
}

// ---------------- fused up2 + conv3x3: quad kernel (2x2 outputs per thread) --------------
template<int CI, int CO, int HI, int WI, int RELU>
__global__ __launch_bounds__(256) void upconv_quad_kernel(const float* __restrict__ in,
                                                          const float* __restrict__ W,
                                                          const float* __restrict__ bias,
                                                          float* __restrict__ out) {
    const int qid = blockIdx.x * 256 + threadIdx.x;
    const int p = qid / WI, q = qid % WI;
    const int co = blockIdx.y, b = blockIdx.z;
    const int HO = HI * 2, WO = WI * 2;
    int off[3][3];
    float msk[3][3];
    #pragma unroll
    for (int r = 0; r < 3; ++r) {
        int pr = p - 1 + r;
        float rm = (pr >= 0 && pr < HI) ? 1.f : 0.f;
        int prc = min(max(pr, 0), HI - 1);
        #pragma unroll
        for (int c = 0; c < 3; ++c) {
            int qc = q - 1 + c;
            float cm = (qc >= 0 && qc < WI) ? 1.f : 0.f;
            int qcc = min(max(qc, 0), WI - 1);
            off[r][c] = prc * WI + qcc;
            msk[r][c] = rm * cm;
        }
    }
    const float* inb = in + (size_t)(b * CI) * HI * WI;
    const float* wco = W + (size_t)co * CI * 9;
    float bb = bias[co];
    float a00 = bb, a01 = bb, a10 = bb, a11 = bb;
    const int me[3] = {0, 1, 1}, mo[3] = {1, 1, 2};
    #pragma unroll 4
    for (int ci = 0; ci < CI; ++ci) {
        const float* ip = inb + (size_t)ci * HI * WI;
        const float* wp = wco + ci * 9;
        float v[3][3];
        #pragma unroll
        for (int r = 0; r < 3; ++r)
            #pragma unroll
            for (int c = 0; c < 3; ++c)
                v[r][c] = msk[r][c] * ip[off[r][c]];
        #pragma unroll
        for (int dy = 0; dy < 3; ++dy) {
            #pragma unroll
            for (int dx = 0; dx < 3; ++dx) {
                float w = wp[dy * 3 + dx];
                a00 += w * v[me[dy]][me[dx]];
                a01 += w * v[me[dy]][mo[dx]];
                a10 += w * v[mo[dy]][me[dx]];
                a11 += w * v[mo[dy]][mo[dx]];
            }
        }
    }
    if (RELU) {
        a00 = lrelu(a00, 0.2f); a01 = lrelu(a01, 0.2f);
        a10 = lrelu(a10, 0.2f); a11 = lrelu(a11, 0.2f);
    }
    float* ob = out + ((size_t)(b * CO + co) * HO + 2 * p) * WO + 2 * q;
    float2 r0 = {a00, a01}, r1 = {a10, a11};
    *(float2*)ob = r0;
    *(float2*)(ob + WO) = r1;
}

extern "C" void kernel_launch(void* const* d_in, const int* in_sizes, int n_in,
                              void* d_out, int out_size, void* d_ws, size_t ws_size,
                              hipStream_t stream) {
    const float* x   = (const float*)d_in[0];
    const float* Wc  = (const float*)d_in[1];
    const float* bc  = (const float*)d_in[2];
    const float* W1  = (const float*)d_in[3];
    const float* b1  = (const float*)d_in[4];
    const float* W2  = (const float*)d_in[5];
    const float* b2  = (const float*)d_in[6];
    const float* W3  = (const float*)d_in[7];
    const float* b3  = (const float*)d_in[8];
    const float* W4  = (const float*)d_in[9];
    const float* b4  = (const float*)d_in[10];
    const float* W5  = (const float*)d_in[11];
    const float* b5  = (const float*)d_in[12];
    const float* Wfc = (const float*)d_in[13];
    const float* bfc = (const float*)d_in[14];
    const float* Wd1 = (const float*)d_in[15];
    const float* bd1 = (const float*)d_in[16];
    const float* Wd2 = (const float*)d_in[17];
    const float* bd2 = (const float*)d_in[18];
    const float* Wd3 = (const float*)d_in[19];
    const float* bd3 = (const float*)d_in[20];
    float* out = (float*)d_out;

    const long NST = (long)N_PTS * N_PTS;                 // NEGD batch stride (elements)
    const size_t NEED_BATCHED = 16809984ull + 33554432ull + 1728512ull;  // 52,092,928
    const bool batched = ws_size >= NEED_BATCHED;
    const size_t negd_bytes = batched ? 33554432ull : 16777216ull;

    char* ws = (char*)d_ws;
    float* Hb   = (float*)(ws + 0);          // (B,N,2)
    float* CAT  = (float*)(ws + 32768);      // (B,N,512)    8 MB
    float* YaT  = (float*)(ws + 8421376);    // (B,N,256)    4 MB
    float* ZT   = (float*)(ws + 12615680);   // (B,N,256)    4 MB
    float* NEGD = (float*)(ws + 16809984);   // (B?,N,N)  16/32 MB
    short* CATh = (short*)(ws + 16809984);   // aliases NEGD after stages (10 MB used)
    short* CATl = (short*)(ws + 21004288);
    short* W5h  = (short*)(ws + 25198592);
    short* W5l  = (short*)(ws + 26247168);
    char* tail  = ws + 16809984 + negd_bytes;
    float* XX   = (float*)(tail);            // 16 KB
    int*   IDX  = (int*)  (tail + 16384);    // 640 KB
    float* PART = (float*)(tail + 671744);   // 128 KB
    float* G    = (float*)(tail + 802816);   // 8 KB
    float* D0   = (float*)(tail + 811008);   // 128 KB
    float* DEC1 = (float*)(tail + 942080);   // 256 KB
    float* DEC2 = (float*)(tail + 1204224);  // 512 KB

    prefix_kernel<<<16, 256, 0, stream>>>(x, Wc, bc, Hb);

    // ---- stage 1: C=2, O=64 ----
    xx_kernel<<<16, 256, 0, stream>>>(Hb, 2, (long)N_PTS * 2, 2, XX);
    if (batched) {
        gram_small_kernel<<<dim3(32, 32, 2), 256, 0, stream>>>(Hb, (long)N_PTS * 2, NST, XX, NEGD);
        topk_kernel<1><<<dim3(N_PTS, 2), 256, 0, stream>>>(NEGD, NST, IDX);
    } else {
        for (int b = 0; b < BATCH; ++b) {
            gram_small_kernel<<<dim3(32, 32, 1), 256, 0, stream>>>(Hb + (size_t)b * N_PTS * 2, 0,
                                                                   0, XX + b * N_PTS, NEGD);
            topk_kernel<1><<<dim3(N_PTS, 1), 256, 0, stream>>>(NEGD, 0,
                                                               IDX + (size_t)b * N_PTS * KNN);
        }
    }
    ya_z_kernel<2, 64, 1><<<dim3(32, 1, BATCH), 256, 0, stream>>>(Hb, 2, (long)N_PTS * 2,
                                                                  W1, b1, YaT, ZT);
    edge_reduce_kernel<64, 1><<<dim3(N_PTS * 64 / 256, BATCH), 256, 0, stream>>>(YaT, ZT, IDX,
                                                                                 CAT, 0);
    // ---- stage 2: C=64, O=64 ----
    xx_kernel<<<16, 256, 0, stream>>>(CAT + 0, 512, (long)N_PTS * 512, 64, XX);
    if (batched) {
        gram_kernel<64, 2><<<dim3(16, 16, 2), 512, 0, stream>>>(CAT + 0, 512, (long)N_PTS * 512,
                                                                NST, XX, NEGD);
        topk_kernel<2><<<dim3(N_PTS, 2), 256, 0, stream>>>(NEGD, NST, IDX);
    } else {
        for (int b = 0; b < BATCH; ++b) {
            gram_kernel<64, 2><<<dim3(16, 16, 1), 512, 0, stream>>>(
                CAT + 0 + (size_t)b * N_PTS * 512, 512, 0, 0, XX + b * N_PTS, NEGD);
            topk_kernel<2><<<dim3(N_PTS, 1), 256, 0, stream>>>(NEGD, 0,
                                                               IDX + (size_t)b * N_PTS * KNN);
        }
    }
    ya_z_kernel<64, 64, 2><<<dim3(32, 1, BATCH), 256, 0, stream>>>(CAT + 0, 512,
                                                                   (long)N_PTS * 512,
                                                                   W2, b2, YaT, ZT);
    edge_reduce_kernel<64, 2><<<dim3(N_PTS * 64 / 256, BATCH), 256, 0, stream>>>(YaT, ZT, IDX,
                                                                                 CAT, 64);
    // ---- stage 3: C=64, O=128 ----
    xx_kernel<<<16, 256, 0, stream>>>(CAT + 64, 512, (long)N_PTS * 512, 64, XX);
    if (batched) {
        gram_kernel<64, 3><<<dim3(16, 16, 2), 512, 0, stream>>>(CAT + 64, 512, (long)N_PTS * 512,
                                                                NST, XX, NEGD);
        topk_kernel<3><<<dim3(N_PTS, 2), 256, 0, stream>>>(NEGD, NST, IDX);
    } else {
        for (int b = 0; b < BATCH; ++b) {
            gram_kernel<64, 3><<<dim3(16, 16, 1), 512, 0, stream>>>(
                CAT + 64 + (size_t)b * N_PTS * 512, 512, 0, 0, XX + b * N_PTS, NEGD);
            topk_kernel<3><<<dim3(N_PTS, 1), 256, 0, stream>>>(NEGD, 0,
                                                               IDX + (size_t)b * N_PTS * KNN);
        }
    }
    ya_z_kernel<64, 128, 3><<<dim3(32, 2, BATCH), 256, 0, stream>>>(CAT + 64, 512,
                                                                    (long)N_PTS * 512,
                                                                    W3, b3, YaT, ZT);
    edge_reduce_kernel<128, 3><<<dim3(N_PTS * 128 / 256, BATCH), 256, 0, stream>>>(YaT, ZT, IDX,
                                                                                   CAT, 128);
    // ---- stage 4: C=128, O=256 ----
    xx_kernel<<<16, 256, 0, stream>>>(CAT + 128, 512, (long)N_PTS * 512, 128, XX);
    if (batched) {
        gram_kernel<128, 4><<<dim3(16, 16, 2), 512, 0, stream>>>(CAT + 128, 512,
                                                                 (long)N_PTS * 512, NST, XX, NEGD);
        topk_kernel<4><<<dim3(N_PTS, 2), 256, 0, stream>>>(NEGD, NST, IDX);
    } else {
        for (int b = 0; b < BATCH; ++b) {
            gram_kernel<128, 4><<<dim3(16, 16, 1), 512, 0, stream>>>(
                CAT + 128 + (size_t)b * N_PTS * 512, 512, 0, 0, XX + b * N_PTS, NEGD);
            topk_kernel<4><<<dim3(N_PTS, 1), 256, 0, stream>>>(NEGD, 0,
                                                               IDX + (size_t)b * N_PTS * KNN);
        }
    }
    ya_z_kernel<128, 256, 4><<<dim3(32, 4, BATCH), 256, 0, stream>>>(CAT + 128, 512,
                                                                     (long)N_PTS * 512,
                                                                     W4, b4, YaT, ZT);
    edge_reduce_kernel<256, 4><<<dim3(N_PTS * 256 / 256, BATCH), 256, 0, stream>>>(YaT, ZT, IDX,
                                                                                   CAT, 256);

    // ---- global feature: split-bf16 MFMA W5 + max ----
    cvt_split_kernel<<<(BATCH * N_PTS * 512 / 4 + 255) / 256, 256, 0, stream>>>(
        CAT, CATh, CATl, BATCH * N_PTS * 512 / 4);
    cvt_split_kernel<<<(1024 * 512 / 4 + 255) / 256, 256, 0, stream>>>(
        W5, W5h, W5l, 1024 * 512 / 4);
    w5max_mfma_kernel<<<dim3(16, 8, BATCH), 256, 0, stream>>>(CATh, CATl, W5h, W5l, b5, PART);
    greduce_kernel<<<8, 256, 0, stream>>>(PART, G);
    fc_kernel<<<4096, 256, 0, stream>>>(G, Wfc, bfc, D0);

    // ---- decoder: quad upconvs ----
    upconv_quad_kernel<64, 32, 16, 16, 1><<<dim3(1, 32, BATCH), 256, 0, stream>>>(D0, Wd1, bd1,
                                                                                  DEC1);
    upconv_quad_kernel<32, 16, 32, 32, 1><<<dim3(4, 16, BATCH), 256, 0, stream>>>(DEC1, Wd2, bd2,
                                                                                  DEC2);
    upconv_quad_kernel<16, 1, 64, 64, 0><<<dim3(16, 1, BATCH), 256, 0, stream>>>(DEC2, Wd3, bd3,
                                                                                 out);
}